// Round 4
// baseline (5721.104 us; speedup 1.0000x reference)
//
#include <hip/hip_runtime.h>

// ---------------------------------------------------------------------------
// GRU decoder w/ attention. Round 4: single persistent loop kernel.
// R3 post-mortem: ~20us per dispatch boundary dominates (130 dispatches).
// Now: upfront kernel (static data) + ONE persistent kernel for all 32 steps.
// Cross-block data uses relaxed agent-scope atomics (sc0/sc1, LLC-coherent,
// NO cache flushes); phase sync via monotonic per-phase counters:
//   producer: stores -> vmcnt(0) -> __syncthreads -> fetch_add(relaxed,agent)
//   consumer: tid0 spins on relaxed agent load -> __syncthreads
// Read-only arrays (bf16 weights, EGI/EREAD/ATTPRE/ctxT) come from the
// upfront kernel through the dispatch boundary -> normal cached loads.
// ---------------------------------------------------------------------------

typedef unsigned short u16;
typedef unsigned long long u64;
using bf16x8 = __attribute__((ext_vector_type(8))) short;
using f32x4  = __attribute__((ext_vector_type(4))) float;

// ---- f32 workspace offsets ----
#define OFF_EGI    0           // [32][64][1536] emb part of gi0 (+b_ih0)   static
#define OFF_EREAD  3145728     // [32][64][512]  emb part of readout        static
#define OFF_ATTPRE 4194304     // [64*128][512]  attn precompute            static
#define OFF_GI0    8388608     // [64][1536] mutable (agent)
#define OFF_GH0    8486912
#define OFF_GH1    8585216
#define OFF_GI1    8683520
#define OFF_RO0    8781824     // [64][512]
#define OFF_RO1    8814592
#define OFF_H0     8847360     // [2][64][512]
#define OFF_H1     8912896
#define OFF_CTX    8978432     // ends 9043968 f32 (= byte 36175872)

// ---- u16 (bf16) offsets relative to (u16*)wsf ----
#define UB_WIH0C   18087936    // [1536][512] static
#define UB_WHH0    18874368
#define UB_WHH1    19660800
#define UB_WIH1    20447232
#define UB_WRO     21233664    // [512][512]
#define UB_WRC     21495808
#define UB_CTXT    21757952    // [64][128][512] static
#define UB_H0B     25952256    // [64][512] mutable (agent)
#define UB_H1B     25985024
#define UB_CTXB    26017792
#define UB_WQ      26050560    // [512][512] static; ends 26312704 u16

// ---- counters: f32 offset (byte 52641792), 33 steps x 6 phases x 32-u32 ----
#define OFF_CNT    13160448
#define CNT_BYTES  25344
// phase ids
#define PH_A  0   // gi0+gh0+gh1 done (72)
#define PH_RO 1   // RO0+RO1 done (16)
#define PH_B  2   // h0 combine done (16)
#define PH_M  3   // maxout done (8)
#define PH_C  4   // gi1 done (24)
#define PH_D  5   // attention done (64)

// ---- output layout (float offsets into d_out) ----
#define OO_G    0
#define OO_C    524288
#define OO_CP   786432
#define OO_HID  788480
#define OO_AL   854016
#define OO_CTXF 862208

__device__ __forceinline__ float sigm(float x) {
    return 1.0f / (1.0f + __expf(-x));
}
__device__ __forceinline__ float tanh_(float x) {
    x = fmaxf(x, -15.f);
    float e = __expf(-2.0f * x);
    return (1.0f - e) / (1.0f + e);
}
__device__ __forceinline__ float gru_out(float ir, float iz, float in_,
                                         float hr, float hz, float hn, float hp) {
    float r = sigm(ir + hr), z = sigm(iz + hz);
    float n = tanh_(in_ + r * hn);
    return (1.f - z) * n + z * hp;
}
__device__ __forceinline__ u16 f2b(float x) {
    unsigned u = __float_as_uint(x);
    return (u16)((u + 0x7FFFu + ((u >> 16) & 1u)) >> 16);
}
__device__ __forceinline__ float b2f(unsigned u) {
    return __uint_as_float(u << 16);
}

// ---- agent-coherent (LLC) accessors: per-access coherence, no flushes ----
__device__ __forceinline__ u64 lda8(const void* p) {
    return __hip_atomic_load((const u64*)p, __ATOMIC_RELAXED, __HIP_MEMORY_SCOPE_AGENT);
}
__device__ __forceinline__ void sta8(void* p, u64 v) {
    __hip_atomic_store((u64*)p, v, __ATOMIC_RELAXED, __HIP_MEMORY_SCOPE_AGENT);
}
__device__ __forceinline__ void sta4(void* p, unsigned v) {
    __hip_atomic_store((unsigned*)p, v, __ATOMIC_RELAXED, __HIP_MEMORY_SCOPE_AGENT);
}
__device__ __forceinline__ void staf(float* p, float v) {
    __hip_atomic_store(p, v, __ATOMIC_RELAXED, __HIP_MEMORY_SCOPE_AGENT);
}
__device__ __forceinline__ float flo(u64 v) { return __uint_as_float((unsigned)v); }
__device__ __forceinline__ float fhi(u64 v) { return __uint_as_float((unsigned)(v >> 32)); }
__device__ __forceinline__ u64 pk2(float a, float b) {
    return (u64)__float_as_uint(a) | ((u64)__float_as_uint(b) << 32);
}

// ---- phase counters ----
__device__ __forceinline__ unsigned* cptr(float* wsf, int t, int ph) {
    return (unsigned*)(wsf + OFF_CNT) + (((t * 6) + ph) << 5);
}
__device__ __forceinline__ void bar_wait(unsigned* c, unsigned tgt) {
    if (threadIdx.x == 0) {
        while (__hip_atomic_load(c, __ATOMIC_RELAXED, __HIP_MEMORY_SCOPE_AGENT) < tgt) {
            __builtin_amdgcn_s_sleep(1);
        }
    }
    __syncthreads();
}
__device__ __forceinline__ void bar_arrive(unsigned* c) {
    // each wave: ensure its agent stores are acked at LLC, then block-sync,
    // then one arrival add (relaxed -> no cache maintenance).
    asm volatile("s_waitcnt vmcnt(0)" ::: "memory");
    __syncthreads();
    if (threadIdx.x == 0)
        __hip_atomic_fetch_add(c, 1u, __ATOMIC_RELAXED, __HIP_MEMORY_SCOPE_AGENT);
}

// ========== f32 tiled GEMM (upfront only) ==========
__device__ __forceinline__ void gemm64(
    const float* __restrict__ xrow, const float* __restrict__ wrow,
    int kt0, int nkt, float* lds_x, float* lds_w,
    float* __restrict__ outp, int JW, int orow0, int j0,
    const float* __restrict__ addp, int addmode, int addJW)
{
    const int tid = threadIdx.x;
    const int tb4 = tid >> 4, tj4 = tid & 15;
    float acc[4][4];
#pragma unroll
    for (int a = 0; a < 4; ++a)
#pragma unroll
        for (int b = 0; b < 4; ++b) acc[a][b] = 0.f;

    for (int kt = kt0; kt < kt0 + nkt; ++kt) {
        const int kb = kt << 6;
        __syncthreads();
        {
            const int rl = tid >> 2;
#pragma unroll
            for (int i = 0; i < 4; ++i) {
                const int kk = ((tid & 3) << 4) + (i << 2);
                float4 xv = *(const float4*)(xrow + kb + kk);
                float4 wv = *(const float4*)(wrow + kb + kk);
                lds_x[(kk + 0) * 64 + rl] = xv.x;
                lds_x[(kk + 1) * 64 + rl] = xv.y;
                lds_x[(kk + 2) * 64 + rl] = xv.z;
                lds_x[(kk + 3) * 64 + rl] = xv.w;
                lds_w[(kk + 0) * 64 + rl] = wv.x;
                lds_w[(kk + 1) * 64 + rl] = wv.y;
                lds_w[(kk + 2) * 64 + rl] = wv.z;
                lds_w[(kk + 3) * 64 + rl] = wv.w;
            }
        }
        __syncthreads();
#pragma unroll 4
        for (int kk = 0; kk < 64; ++kk) {
            float4 xv = *(const float4*)(lds_x + kk * 64 + tb4 * 4);
            float4 wv = *(const float4*)(lds_w + kk * 64 + tj4 * 4);
            acc[0][0] += xv.x * wv.x; acc[0][1] += xv.x * wv.y;
            acc[0][2] += xv.x * wv.z; acc[0][3] += xv.x * wv.w;
            acc[1][0] += xv.y * wv.x; acc[1][1] += xv.y * wv.y;
            acc[1][2] += xv.y * wv.z; acc[1][3] += xv.y * wv.w;
            acc[2][0] += xv.z * wv.x; acc[2][1] += xv.z * wv.y;
            acc[2][2] += xv.z * wv.z; acc[2][3] += xv.z * wv.w;
            acc[3][0] += xv.w * wv.x; acc[3][1] += xv.w * wv.y;
            acc[3][2] += xv.w * wv.z; acc[3][3] += xv.w * wv.w;
        }
    }
#pragma unroll
    for (int ib = 0; ib < 4; ++ib) {
        const int row = tb4 * 4 + ib;
        const int jc = j0 + tj4 * 4;
        float4 r;
        r.x = acc[ib][0]; r.y = acc[ib][1]; r.z = acc[ib][2]; r.w = acc[ib][3];
        if (addmode == 1) {
            float4 bv = *(const float4*)(addp + jc);
            r.x += bv.x; r.y += bv.y; r.z += bv.z; r.w += bv.w;
        } else if (addmode == 2) {
            float4 bv = *(const float4*)(addp + (size_t)(orow0 + row) * addJW + jc);
            r.x += bv.x; r.y += bv.y; r.z += bv.z; r.w += bv.w;
        }
        *(float4*)(outp + (size_t)(orow0 + row) * JW + jc) = r;
    }
}

// ========== bf16 MFMA GEMM: D[64x64] = X[64x512] @ W[64x512]^T ==========
// X staged in LDS via agent loads (mutable state); W/bias via normal loads.
__device__ __forceinline__ void stage_coh(const u16* __restrict__ Xg, u16* sX) {
    const int tid = threadIdx.x;
#pragma unroll
    for (int p = 0; p < 16; ++p) {
        const int chunk = p * 256 + tid;          // 4096 chunks of 16B
        const int row = chunk >> 6, cb16 = chunk & 63;
        const int src = row * 1024 + cb16 * 16;   // bytes
        const int dst = src ^ ((row & 7) << 4);   // XOR-swizzle within row
        u64 a = lda8((const char*)Xg + src);
        u64 b = lda8((const char*)Xg + src + 8);
        *(u64*)((char*)sX + dst) = a;
        *(u64*)((char*)sX + dst + 8) = b;
    }
}

// mode 0: store; 1: +addp[col]; 2: +addp[row*addJW+col]. (addp pre-offset by j0)
// outputs stored with agent-scope coherence.
__device__ __forceinline__ void mfma_gemm64(const u16* sX, const u16* __restrict__ Wg,
        float* __restrict__ outp, int JW,
        const float* __restrict__ addp, int mode, int addJW)
{
    const int tid = threadIdx.x;
    const int w = tid >> 6, l = tid & 63;
    const int l15 = l & 15, lhi = l >> 4;
    f32x4 acc0 = {0.f,0.f,0.f,0.f}, acc1 = acc0, acc2 = acc0, acc3 = acc0;
    const int arow = w * 16 + l15;
    const char* aptr = (const char*)sX;
    const int abase = arow * 1024 + lhi * 16;
    const int aswz = (arow & 7) << 4;
#pragma unroll 4
    for (int ks = 0; ks < 16; ++ks) {
        bf16x8 a = *(const bf16x8*)(aptr + ((abase + ks * 64) ^ aswz));
        const u16* wp = Wg + l15 * 512 + ks * 32 + lhi * 8;
        bf16x8 b0 = *(const bf16x8*)(wp);
        bf16x8 b1 = *(const bf16x8*)(wp + 16 * 512);
        bf16x8 b2 = *(const bf16x8*)(wp + 32 * 512);
        bf16x8 b3 = *(const bf16x8*)(wp + 48 * 512);
        acc0 = __builtin_amdgcn_mfma_f32_16x16x32_bf16(a, b0, acc0, 0, 0, 0);
        acc1 = __builtin_amdgcn_mfma_f32_16x16x32_bf16(a, b1, acc1, 0, 0, 0);
        acc2 = __builtin_amdgcn_mfma_f32_16x16x32_bf16(a, b2, acc2, 0, 0, 0);
        acc3 = __builtin_amdgcn_mfma_f32_16x16x32_bf16(a, b3, acc3, 0, 0, 0);
    }
    f32x4 accs[4] = {acc0, acc1, acc2, acc3};
#pragma unroll
    for (int cb = 0; cb < 4; ++cb) {
        const int col = cb * 16 + l15;
#pragma unroll
        for (int r = 0; r < 4; ++r) {
            const int row = w * 16 + lhi * 4 + r;
            float v = accs[cb][r];
            if (mode == 1) v += addp[col];
            else if (mode == 2) v += addp[row * addJW + col];
            staf(outp + (size_t)row * JW + col, v);
        }
    }
}

// =================== upfront: all static data + state init ===================
__global__ __launch_bounds__(256)
void k_upfront(const int* __restrict__ inp, const float* __restrict__ hid,
               const float* __restrict__ ctxin, const float* __restrict__ init_att,
               const float* __restrict__ embW,
               const float* __restrict__ W_ih0, const float* __restrict__ b_ih0,
               const float* __restrict__ W_hh0, const float* __restrict__ W_hh1,
               const float* __restrict__ W_ih1, const float* __restrict__ W_q,
               const float* __restrict__ W_read, const float* __restrict__ b_read,
               const float* __restrict__ W_pre, const float* __restrict__ b_pre,
               float* __restrict__ wsf)
{
    __shared__ float lds_x[4096], lds_w[4096];
    u16* wsu = (u16*)wsf;
    const int jid = blockIdx.x, tid = threadIdx.x, rl = tid >> 2;
    if (jid < 768) {
        const int mt = jid / 24, jt = jid % 24, j0 = jt << 6;
        const int idx = inp[mt * 64 + rl];
        gemm64(embW + (size_t)idx * 512, W_ih0 + (size_t)(j0 + rl) * 1024,
               0, 8, lds_x, lds_w, wsf + OFF_EGI, 1536, mt << 6, j0, b_ih0, 1, 0);
    } else if (jid < 1024) {
        const int r = jid - 768, mt = r >> 3, jt = r & 7, j0 = jt << 6;
        const int idx = inp[mt * 64 + rl];
        gemm64(embW + (size_t)idx * 512, W_read + (size_t)(j0 + rl) * 1536,
               0, 8, lds_x, lds_w, wsf + OFF_EREAD, 512, mt << 6, j0, b_read, 1, 0);
    } else if (jid < 2048) {
        const int r = jid - 1024, mt = r >> 3, jt = r & 7, j0 = jt << 6;
        const int m = (mt << 6) + rl, b = m >> 7, s = m & 127;
        gemm64(ctxin + (size_t)((s << 6) + b) * 512, W_pre + (size_t)(j0 + rl) * 512,
               0, 8, lds_x, lds_w, wsf + OFF_ATTPRE, 512, mt << 6, j0, b_pre, 1, 0);
    } else if (jid < 2054) {
        // f32 state init at slot 1 (t=0 has prv=1) — write agent-coherent
        const int job = jid - 2048, buf = job >> 1, half = job & 1;
        const float* src = buf == 0 ? hid : (buf == 1 ? hid + 32768 : init_att);
        float* dst = wsf + (buf == 0 ? OFF_H0 : (buf == 1 ? OFF_H1 : OFF_CTX)) + 32768;
        for (int i = 0; i < 32; ++i) {
            int e = (half * 16384 + i * 512 + tid * 2);
            sta8(dst + e, pk2(src[e], src[e + 1]));
        }
    } else if (jid < 2278) {
        // weight conversions to bf16
        const int w = jid - 2054;
        if (w < 48) {
            for (int i = 0; i < 64; ++i) {
                int e = w * 16384 + i * 256 + tid;
                int j = e >> 9, k = e & 511;
                wsu[UB_WIH0C + e] = f2b(W_ih0[(size_t)j * 1024 + 512 + k]);
            }
        } else if (w < 96) {
            for (int i = 0; i < 64; ++i) {
                int e = (w - 48) * 16384 + i * 256 + tid;
                wsu[UB_WHH0 + e] = f2b(W_hh0[e]);
            }
        } else if (w < 144) {
            for (int i = 0; i < 64; ++i) {
                int e = (w - 96) * 16384 + i * 256 + tid;
                wsu[UB_WHH1 + e] = f2b(W_hh1[e]);
            }
        } else if (w < 192) {
            for (int i = 0; i < 64; ++i) {
                int e = (w - 144) * 16384 + i * 256 + tid;
                wsu[UB_WIH1 + e] = f2b(W_ih1[e]);
            }
        } else if (w < 208) {
            for (int i = 0; i < 64; ++i) {
                int e = (w - 192) * 16384 + i * 256 + tid;
                int j = e >> 9, k = e & 511;
                wsu[UB_WRO + e] = f2b(W_read[(size_t)j * 1536 + 512 + k]);
            }
        } else {
            for (int i = 0; i < 64; ++i) {
                int e = (w - 208) * 16384 + i * 256 + tid;
                int j = e >> 9, k = e & 511;
                wsu[UB_WRC + e] = f2b(W_read[(size_t)j * 1536 + 1024 + k]);
            }
        }
    } else if (jid < 2534) {
        // ctxT bf16 [b][s][e]
        const int w2 = jid - 2278;
        for (int rr = 0; rr < 32; ++rr) {
            const int r = w2 * 32 + rr;
            const int b = r >> 7, s = r & 127;
            const float* src = ctxin + ((size_t)s * 64 + b) * 512;
#pragma unroll
            for (int h = 0; h < 2; ++h) {
                int e = h * 256 + tid;
                wsu[UB_CTXT + (size_t)r * 512 + e] = f2b(src[e]);
            }
        }
    } else if (jid < 2537) {
        // bf16 state shadows — agent-coherent
        const int job = jid - 2534;
        const float* src = job == 0 ? hid : (job == 1 ? hid + 32768 : init_att);
        u16* dst = wsu + (job == 0 ? UB_H0B : (job == 1 ? UB_H1B : UB_CTXB));
        for (int i = 0; i < 64; ++i) {
            int e = (i * 256 + tid) * 2;
            sta4(dst + e, (unsigned)f2b(src[e]) | ((unsigned)f2b(src[e + 1]) << 16));
        }
    } else {
        // W_q bf16
        const int w3 = jid - 2537;
        for (int i = 0; i < 64; ++i) {
            int e = w3 * 16384 + i * 256 + tid;
            wsu[UB_WQ + e] = f2b(W_q[e]);
        }
    }
}

// =================== persistent loop kernel (88 blocks) ===================
__global__ __launch_bounds__(256)
void k_loop(const float* __restrict__ b_hh0, const float* __restrict__ b_hh1,
            const float* __restrict__ b_ih1, const float* __restrict__ maskp,
            const float* __restrict__ w_v, const float* __restrict__ W_copy,
            const float* __restrict__ b_copy, float* __restrict__ wsf,
            float* __restrict__ dout)
{
    __shared__ u16 sX[64 * 512];
    u16* wsu = (u16*)wsf;
    const int blk = blockIdx.x, tid = threadIdx.x;

    for (int t = 0; t < 32; ++t) {
        const int cur = t & 1, prv = cur ^ 1;

        // ---------- phase A: gi0 / gh0 / gh1 / RO(t-1) ----------
        if (blk < 88) {
            if (t > 0) bar_wait(cptr(wsf, t - 1, PH_D), 64);
            if (blk >= 72 && t >= 2) bar_wait(cptr(wsf, t - 1, PH_M), 8);
            if (blk < 24) {
                stage_coh(wsu + UB_CTXB, sX); __syncthreads();
                mfma_gemm64(sX, wsu + UB_WIH0C + blk * 32768, wsf + OFF_GI0 + (blk << 6), 1536,
                            wsf + OFF_EGI + (size_t)t * 98304 + (blk << 6), 2, 1536);
                bar_arrive(cptr(wsf, t, PH_A));
            } else if (blk < 48) {
                const int jt = blk - 24;
                stage_coh(wsu + UB_H0B, sX); __syncthreads();
                mfma_gemm64(sX, wsu + UB_WHH0 + jt * 32768, wsf + OFF_GH0 + (jt << 6), 1536,
                            b_hh0 + (jt << 6), 1, 0);
                bar_arrive(cptr(wsf, t, PH_A));
            } else if (blk < 72) {
                const int jt = blk - 48;
                stage_coh(wsu + UB_H1B, sX); __syncthreads();
                mfma_gemm64(sX, wsu + UB_WHH1 + jt * 32768, wsf + OFF_GH1 + (jt << 6), 1536,
                            b_hh1 + (jt << 6), 1, 0);
                bar_arrive(cptr(wsf, t, PH_A));
            } else if (blk < 80) {
                if (t > 0) {
                    const int jt = blk - 72;
                    stage_coh(wsu + UB_H1B, sX); __syncthreads();
                    mfma_gemm64(sX, wsu + UB_WRO + jt * 32768, wsf + OFF_RO0 + (jt << 6), 512,
                                nullptr, 0, 0);
                    bar_arrive(cptr(wsf, t, PH_RO));
                }
            } else {
                if (t > 0) {
                    const int jt = blk - 80;
                    stage_coh(wsu + UB_CTXB, sX); __syncthreads();
                    mfma_gemm64(sX, wsu + UB_WRC + jt * 32768, wsf + OFF_RO1 + (jt << 6), 512,
                                nullptr, 0, 0);
                    bar_arrive(cptr(wsf, t, PH_RO));
                }
            }
        }

        // ---------- phase B: h0 combine (0..15) | maxout(t-1) (16..23) ----------
        if (blk < 16) {
            bar_wait(cptr(wsf, t, PH_A), 72);
            float* h0_cur = wsf + OFF_H0 + cur * 32768;
            const float* h0_prv = wsf + OFF_H0 + prv * 32768;
            const float* GIp = wsf + OFF_GI0;
            const float* GHp = wsf + OFF_GH0;
            u16* h0b = wsu + UB_H0B;
#pragma unroll
            for (int i = 0; i < 4; ++i) {
                const int p = (blk << 10) + (i << 8) + tid;  // pair index
                const int b = p >> 8, c0 = (p & 255) * 2;
                const int base = b * 1536 + c0;
                u64 gr = lda8(GIp + base), gz = lda8(GIp + base + 512), gn = lda8(GIp + base + 1024);
                u64 hr = lda8(GHp + base), hz = lda8(GHp + base + 512), hn = lda8(GHp + base + 1024);
                u64 hp = lda8(h0_prv + b * 512 + c0);
                float o0 = gru_out(flo(gr), flo(gz), flo(gn), flo(hr), flo(hz), flo(hn), flo(hp));
                float o1 = gru_out(fhi(gr), fhi(gz), fhi(gn), fhi(hr), fhi(hz), fhi(hn), fhi(hp));
                sta8(h0_cur + b * 512 + c0, pk2(o0, o1));
                sta4(h0b + b * 512 + c0, (unsigned)f2b(o0) | ((unsigned)f2b(o1) << 16));
            }
            bar_arrive(cptr(wsf, t, PH_B));
        } else if (blk < 24 && t > 0) {
            bar_wait(cptr(wsf, t, PH_RO), 16);
            const int r = blk - 16;
            const float* ERp = wsf + OFF_EREAD + (size_t)(t - 1) * 32768;
            const float* R0 = wsf + OFF_RO0;
            const float* R1 = wsf + OFF_RO1;
#pragma unroll
            for (int i = 0; i < 8; ++i) {
                const int e = (r << 11) + (i << 8) + tid;
                const int b = e >> 8, j2 = e & 255;
                const int bi = b * 512 + (j2 << 1);
                u64 p0 = lda8(R0 + bi);
                u64 p1 = lda8(R1 + bi);
                float v0 = ERp[bi]     + flo(p0) + flo(p1);
                float v1 = ERp[bi + 1] + fhi(p0) + fhi(p1);
                dout[OO_G + (size_t)(t - 1) * 16384 + b * 256 + j2] = fmaxf(v0, v1);
            }
            bar_arrive(cptr(wsf, t, PH_M));
        }

        // ---------- phase C: gi1 (0..23) ----------
        if (blk < 24) {
            bar_wait(cptr(wsf, t, PH_B), 16);
            stage_coh(wsu + UB_H0B, sX); __syncthreads();
            mfma_gemm64(sX, wsu + UB_WIH1 + blk * 32768, wsf + OFF_GI1 + (blk << 6), 1536,
                        b_ih1 + (blk << 6), 1, 0);
            bar_arrive(cptr(wsf, t, PH_C));
        }

        // ---------- phase D: per-b attention (0..63) ----------
        if (blk < 64) {
            bar_wait(cptr(wsf, t, PH_C), 24);
            const int b = blk;
            float* sf = (float*)sX;
            float* s_out = sf;            // 512
            float* s_q   = sf + 512;      // 512
            float* s_e   = sf + 1024;     // 128
            float* s_at  = sf + 1152;     // 128
            float* s_ctx = sf + 1280;     // 512
            float* s_red = sf + 1792;     // 256

            // recombine out[b] from gi1/gh1; publish h1 state
            {
                const float* GI1p = wsf + OFF_GI1 + b * 1536;
                const float* GH1p = wsf + OFF_GH1 + b * 1536;
                const float* h1p  = wsf + OFF_H1 + prv * 32768 + b * 512;
                float* h1c = wsf + OFF_H1 + cur * 32768 + b * 512;
                u16* h1b = wsu + UB_H1B + b * 512;
                const int c0 = tid * 2;
                u64 vr = lda8(GI1p + c0), vz = lda8(GI1p + 512 + c0), vn = lda8(GI1p + 1024 + c0);
                u64 wr = lda8(GH1p + c0), wz = lda8(GH1p + 512 + c0), wn = lda8(GH1p + 1024 + c0);
                u64 hp = lda8(h1p + c0);
                float o0 = gru_out(flo(vr), flo(vz), flo(vn), flo(wr), flo(wz), flo(wn), flo(hp));
                float o1 = gru_out(fhi(vr), fhi(vz), fhi(vn), fhi(wr), fhi(wz), fhi(wn), fhi(hp));
                s_out[c0] = o0; s_out[c0 + 1] = o1;
                sta8(h1c + c0, pk2(o0, o1));
                sta4(h1b + c0, (unsigned)f2b(o0) | ((unsigned)f2b(o1) << 16));
            }
            __syncthreads();

            // q = out @ W_q^T (bf16 weights, static)
            {
                const u16* wq0 = wsu + UB_WQ + (size_t)tid * 512;
                const u16* wq1 = wq0 + (size_t)256 * 512;
                float q0 = 0.f, q1 = 0.f;
#pragma unroll 4
                for (int k = 0; k < 512; k += 4) {
                    float4 ov = *(const float4*)(s_out + k);
                    u64 a0 = *(const u64*)(wq0 + k);
                    u64 a1 = *(const u64*)(wq1 + k);
                    q0 += ov.x * b2f((unsigned)(a0 & 0xffff)) + ov.y * b2f((unsigned)((a0 >> 16) & 0xffff))
                        + ov.z * b2f((unsigned)((a0 >> 32) & 0xffff)) + ov.w * b2f((unsigned)(a0 >> 48));
                    q1 += ov.x * b2f((unsigned)(a1 & 0xffff)) + ov.y * b2f((unsigned)((a1 >> 16) & 0xffff))
                        + ov.z * b2f((unsigned)((a1 >> 32) & 0xffff)) + ov.w * b2f((unsigned)(a1 >> 48));
                }
                s_q[tid] = q0; s_q[tid + 256] = q1;
            }
            __syncthreads();

            // energy[s] = w_v . tanh(pre[b,s,:] + q)   (pre static)
            {
                const int wid = tid >> 6, lane = tid & 63;
                for (int s = wid; s < 128; s += 4) {
                    const float* pre = wsf + OFF_ATTPRE + ((size_t)b * 128 + s) * 512;
                    float acc = 0.f;
#pragma unroll
                    for (int i = 0; i < 8; ++i) {
                        const int a = lane + (i << 6);
                        acc += tanh_(pre[a] + s_q[a]) * w_v[a];
                    }
#pragma unroll
                    for (int d2 = 1; d2 < 64; d2 <<= 1) acc += __shfl_xor(acc, d2, 64);
                    if (lane == 0)
                        s_e[s] = (maskp[b * 128 + s] > 0.5f) ? -3.0e38f : acc;
                }
            }
            __syncthreads();

            // softmax over S=128
            if (tid < 64) {
                float e0 = s_e[tid], e1 = s_e[tid + 64];
                float mx = fmaxf(e0, e1);
#pragma unroll
                for (int d2 = 1; d2 < 64; d2 <<= 1) mx = fmaxf(mx, __shfl_xor(mx, d2, 64));
                float x0 = __expf(e0 - mx), x1 = __expf(e1 - mx);
                float sm = x0 + x1;
#pragma unroll
                for (int d2 = 1; d2 < 64; d2 <<= 1) sm += __shfl_xor(sm, d2, 64);
                float inv = 1.f / sm;
                x0 *= inv; x1 *= inv;
                s_at[tid] = x0; s_at[tid + 64] = x1;
                float* co = dout + OO_C + ((size_t)t * 64 + b) * 128;
                co[tid] = x0; co[tid + 64] = x1;
                if (t == 31) {
                    dout[OO_AL + b * 128 + tid] = x0;
                    dout[OO_AL + b * 128 + tid + 64] = x1;
                }
            }
            __syncthreads();

            // new_ctx = attn @ ctx (ctxT bf16 static); publish ctx state
            {
                const int e0 = tid * 2;
                const u16* ct = wsu + UB_CTXT + (size_t)b * 65536 + e0;
                float a0 = 0.f, a1 = 0.f;
#pragma unroll 4
                for (int s = 0; s < 128; ++s) {
                    float at = s_at[s];
                    unsigned pv = *(const unsigned*)(ct + s * 512);
                    a0 = fmaf(at, b2f(pv & 0xffffu), a0);
                    a1 = fmaf(at, b2f(pv >> 16), a1);
                }
                s_ctx[e0] = a0; s_ctx[e0 + 1] = a1;
                sta8(wsf + OFF_CTX + cur * 32768 + b * 512 + e0, pk2(a0, a1));
                sta4(wsu + UB_CTXB + b * 512 + e0,
                     (unsigned)f2b(a0) | ((unsigned)f2b(a1) << 16));
            }
            __syncthreads();

            // copy gate
            {
                float part = 0.f;
                for (int i2 = tid; i2 < 512; i2 += 256)
                    part += s_out[i2] * W_copy[i2] + s_ctx[i2] * W_copy[512 + i2];
                s_red[tid] = part;
                __syncthreads();
                for (int d2 = 128; d2 > 0; d2 >>= 1) {
                    if (tid < d2) s_red[tid] += s_red[tid + d2];
                    __syncthreads();
                }
                if (tid == 0)
                    dout[OO_CP + t * 64 + b] = sigm(s_red[0] + b_copy[0]);
            }
            bar_arrive(cptr(wsf, t, PH_D));
        }
    }

    // ===================== EPILOGUE =====================
    // final readout (step 32 pseudo-phase) for g_outputs[31]
    if (blk >= 72 && blk < 88) {
        bar_wait(cptr(wsf, 31, PH_D), 64);
        bar_wait(cptr(wsf, 31, PH_M), 8);
        if (blk < 80) {
            const int jt = blk - 72;
            stage_coh(wsu + UB_H1B, sX); __syncthreads();
            mfma_gemm64(sX, wsu + UB_WRO + jt * 32768, wsf + OFF_RO0 + (jt << 6), 512,
                        nullptr, 0, 0);
        } else {
            const int jt = blk - 80;
            stage_coh(wsu + UB_CTXB, sX); __syncthreads();
            mfma_gemm64(sX, wsu + UB_WRC + jt * 32768, wsf + OFF_RO1 + (jt << 6), 512,
                        nullptr, 0, 0);
        }
        bar_arrive(cptr(wsf, 32, PH_RO));
    }
    if (blk >= 16 && blk < 24) {
        bar_wait(cptr(wsf, 32, PH_RO), 16);
        const int r = blk - 16;
        const float* ERp = wsf + OFF_EREAD + (size_t)31 * 32768;
        const float* R0 = wsf + OFF_RO0;
        const float* R1 = wsf + OFF_RO1;
#pragma unroll
        for (int i = 0; i < 8; ++i) {
            const int e = (r << 11) + (i << 8) + tid;
            const int b = e >> 8, j2 = e & 255;
            const int bi = b * 512 + (j2 << 1);
            u64 p0 = lda8(R0 + bi);
            u64 p1 = lda8(R1 + bi);
            float v0 = ERp[bi]     + flo(p0) + flo(p1);
            float v1 = ERp[bi + 1] + fhi(p0) + fhi(p1);
            dout[OO_G + (size_t)31 * 16384 + b * 256 + j2] = fmaxf(v0, v1);
        }
    }
    // final states (slot 1 at t=31)
    if (blk >= 24 && blk < 36) {
        bar_wait(cptr(wsf, 31, PH_D), 64);
        const int job = blk - 24;
        const float* src = wsf + (job < 4 ? OFF_H0 : job < 8 ? OFF_H1 : OFF_CTX)
                         + 32768 + (job & 3) * 8192;
        float* dst = dout + (job < 4 ? OO_HID : job < 8 ? (OO_HID + 32768) : OO_CTXF)
                   + (job & 3) * 8192;
        for (int i = 0; i < 16; ++i) {
            const int e2 = (i * 256 + tid) * 2;
            u64 v = lda8(src + e2);
            *(u64*)(dst + e2) = v;
        }
    }
}

extern "C" void kernel_launch(void* const* d_in, const int* in_sizes, int n_in,
                              void* d_out, int out_size, void* d_ws, size_t ws_size,
                              hipStream_t stream) {
    const int*   inp      = (const int*)d_in[0];
    const float* hid      = (const float*)d_in[1];
    const float* ctxin    = (const float*)d_in[2];
    const float* maskp    = (const float*)d_in[3];
    const float* init_att = (const float*)d_in[4];
    const float* embW     = (const float*)d_in[5];
    const float* W_ih0    = (const float*)d_in[6];
    const float* b_ih0    = (const float*)d_in[7];
    const float* W_hh0    = (const float*)d_in[8];
    const float* b_hh0    = (const float*)d_in[9];
    const float* W_ih1    = (const float*)d_in[10];
    const float* b_ih1    = (const float*)d_in[11];
    const float* W_hh1    = (const float*)d_in[12];
    const float* b_hh1    = (const float*)d_in[13];
    const float* W_pre    = (const float*)d_in[14];
    const float* b_pre    = (const float*)d_in[15];
    const float* W_q      = (const float*)d_in[16];
    const float* w_v      = (const float*)d_in[17];
    const float* W_copy   = (const float*)d_in[18];
    const float* b_copy   = (const float*)d_in[19];
    const float* W_read   = (const float*)d_in[20];
    const float* b_read   = (const float*)d_in[21];
    float* dout = (float*)d_out;
    float* wsf  = (float*)d_ws;

    // zero phase counters (33 steps x 6 phases x 128B)
    hipMemsetAsync((char*)d_ws + (size_t)OFF_CNT * 4, 0, CNT_BYTES, stream);

    k_upfront<<<dim3(2553), dim3(256), 0, stream>>>(
        inp, hid, ctxin, init_att, embW, W_ih0, b_ih0, W_hh0, W_hh1, W_ih1, W_q,
        W_read, b_read, W_pre, b_pre, wsf);

    k_loop<<<dim3(88), dim3(256), 0, stream>>>(
        b_hh0, b_hh1, b_ih1, maskp, w_v, W_copy, b_copy, wsf, dout);
}

// Round 5
// 5644.727 us; speedup vs baseline: 1.0135x; 1.0135x over previous
//
#include <hip/hip_runtime.h>

// ---------------------------------------------------------------------------
// GRU decoder w/ attention. Round 5: persistent kernel + rotating buffers.
// R4 post-mortem: agent-scope (uncached) data loads at 1 wave/SIMD were
// latency-bound (547MB uncached traffic, 2.4% VALUBusy). Now:
//  - mutable state rotates through per-step FRESH addresses (33 slots):
//    producers write-through to LLC (agent stores), consumers do PLAIN cached
//    loads (first touch -> guaranteed miss -> correct LLC data, then L2-hit
//    for redundant readers). No uncached data loads remain.
//  - gate GEMMs computed as (r,z,n) column-triples per block -> h0/h1 combine
//    is block-local; NO gate intermediates in global memory at all.
//  - f32 hidden-state blend values live in REGISTERS across the t-loop
//    (block j owns cols j*64 forever).
//  - out == h1 (layer-1 GRU output), one bf16 shadow serves both.
//  - readout+maxout fused into an 8-block track off the critical path.
// Critical path/step: C[t-1] -> A(8) -> B(8) -> C(64); 3 barriers.
// ---------------------------------------------------------------------------

typedef unsigned short u16;
typedef unsigned long long u64;
using bf16x8 = __attribute__((ext_vector_type(8))) short;
using f32x4  = __attribute__((ext_vector_type(4))) float;

// ---- f32 workspace offsets (static data, written by k_upfront) ----
#define OFF_EGI    0           // [32][64][1536] emb part of gi0 (+b_ih0)
#define OFF_EREAD  3145728     // [32][64][512]  emb part of readout (+b_read)
#define OFF_ATTPRE 4194304     // [64*128][512]  attn precompute (+b_pre)
// (f32 region 8388608..9043968 from prior rounds now unused)

// ---- u16 (bf16) offsets relative to (u16*)wsf ----
#define UB_WIH0C   18087936    // [1536][512] W_ih0 ctx-half      static
#define UB_WHH0    18874368    // [1536][512]
#define UB_WHH1    19660800    // [1536][512]
#define UB_WIH1    20447232    // [1536][512]
#define UB_WRO     21233664    // [512][512]  W_read out-cols
#define UB_WRC     21495808    // [512][512]  W_read ctx-cols
#define UB_CTXT    21757952    // [64][128][512] ctx transposed
#define UB_WQ      26050560    // [512][512]  W_q
// rotating bf16 state shadows: 33 slots x [64][512]; slot 32 = initial state
#define ROT_H0B    26312704
#define ROT_H1B    27394048    // h1 == out
#define ROT_CTXB   28475392    // ends 29556736 u16 (byte 59113472)

// ---- phase counters: 33 steps x 3 phases x 32 u32 ----
#define OFF_CNT    14778368    // f32 offset (byte 59113472)
#define CNT_BYTES  12672
#define PH_A  0   // h0[t] ready (8 arrivals)
#define PH_B  1   // h1/out[t] ready (8)
#define PH_C  2   // ctx[t] ready (64)

// ---- output layout (float offsets into d_out) ----
#define OO_G    0
#define OO_C    524288
#define OO_CP   786432
#define OO_HID  788480
#define OO_AL   854016
#define OO_CTXF 862208

__device__ __forceinline__ float sigm(float x) {
    return 1.0f / (1.0f + __expf(-x));
}
__device__ __forceinline__ float tanh_(float x) {
    x = fmaxf(x, -15.f);
    float e = __expf(-2.0f * x);
    return (1.0f - e) / (1.0f + e);
}
__device__ __forceinline__ u16 f2b(float x) {
    unsigned u = __float_as_uint(x);
    return (u16)((u + 0x7FFFu + ((u >> 16) & 1u)) >> 16);
}
__device__ __forceinline__ float b2f(unsigned u) {
    return __uint_as_float(u << 16);
}

// ---- write-through (LLC-visible) stores; reads are PLAIN on fresh addrs ----
__device__ __forceinline__ void sta8(void* p, u64 v) {
    __hip_atomic_store((u64*)p, v, __ATOMIC_RELAXED, __HIP_MEMORY_SCOPE_AGENT);
}
__device__ __forceinline__ void sta4(void* p, unsigned v) {
    __hip_atomic_store((unsigned*)p, v, __ATOMIC_RELAXED, __HIP_MEMORY_SCOPE_AGENT);
}

// ---- phase counters ----
__device__ __forceinline__ unsigned* cptr(float* wsf, int t, int ph) {
    return (unsigned*)(wsf + OFF_CNT) + (((t * 3) + ph) << 5);
}
__device__ __forceinline__ void bar_wait(unsigned* c, unsigned tgt) {
    if (threadIdx.x == 0) {
        while (__hip_atomic_load(c, __ATOMIC_RELAXED, __HIP_MEMORY_SCOPE_AGENT) < tgt) {
            __builtin_amdgcn_s_sleep(1);
        }
    }
    __syncthreads();
}
__device__ __forceinline__ void bar_arrive(unsigned* c) {
    asm volatile("s_waitcnt vmcnt(0)" ::: "memory");  // drain write-through stores
    __syncthreads();
    if (threadIdx.x == 0)
        __hip_atomic_fetch_add(c, 1u, __ATOMIC_RELAXED, __HIP_MEMORY_SCOPE_AGENT);
}

// ========== f32 tiled GEMM (upfront only) ==========
__device__ __forceinline__ void gemm64(
    const float* __restrict__ xrow, const float* __restrict__ wrow,
    int kt0, int nkt, float* lds_x, float* lds_w,
    float* __restrict__ outp, int JW, int orow0, int j0,
    const float* __restrict__ addp, int addmode, int addJW)
{
    const int tid = threadIdx.x;
    const int tb4 = tid >> 4, tj4 = tid & 15;
    float acc[4][4];
#pragma unroll
    for (int a = 0; a < 4; ++a)
#pragma unroll
        for (int b = 0; b < 4; ++b) acc[a][b] = 0.f;

    for (int kt = kt0; kt < kt0 + nkt; ++kt) {
        const int kb = kt << 6;
        __syncthreads();
        {
            const int rl = tid >> 2;
#pragma unroll
            for (int i = 0; i < 4; ++i) {
                const int kk = ((tid & 3) << 4) + (i << 2);
                float4 xv = *(const float4*)(xrow + kb + kk);
                float4 wv = *(const float4*)(wrow + kb + kk);
                lds_x[(kk + 0) * 64 + rl] = xv.x;
                lds_x[(kk + 1) * 64 + rl] = xv.y;
                lds_x[(kk + 2) * 64 + rl] = xv.z;
                lds_x[(kk + 3) * 64 + rl] = xv.w;
                lds_w[(kk + 0) * 64 + rl] = wv.x;
                lds_w[(kk + 1) * 64 + rl] = wv.y;
                lds_w[(kk + 2) * 64 + rl] = wv.z;
                lds_w[(kk + 3) * 64 + rl] = wv.w;
            }
        }
        __syncthreads();
#pragma unroll 4
        for (int kk = 0; kk < 64; ++kk) {
            float4 xv = *(const float4*)(lds_x + kk * 64 + tb4 * 4);
            float4 wv = *(const float4*)(lds_w + kk * 64 + tj4 * 4);
            acc[0][0] += xv.x * wv.x; acc[0][1] += xv.x * wv.y;
            acc[0][2] += xv.x * wv.z; acc[0][3] += xv.x * wv.w;
            acc[1][0] += xv.y * wv.x; acc[1][1] += xv.y * wv.y;
            acc[1][2] += xv.y * wv.z; acc[1][3] += xv.y * wv.w;
            acc[2][0] += xv.z * wv.x; acc[2][1] += xv.z * wv.y;
            acc[2][2] += xv.z * wv.z; acc[2][3] += xv.z * wv.w;
            acc[3][0] += xv.w * wv.x; acc[3][1] += xv.w * wv.y;
            acc[3][2] += xv.w * wv.z; acc[3][3] += xv.w * wv.w;
        }
    }
#pragma unroll
    for (int ib = 0; ib < 4; ++ib) {
        const int row = tb4 * 4 + ib;
        const int jc = j0 + tj4 * 4;
        float4 r;
        r.x = acc[ib][0]; r.y = acc[ib][1]; r.z = acc[ib][2]; r.w = acc[ib][3];
        if (addmode == 1) {
            float4 bv = *(const float4*)(addp + jc);
            r.x += bv.x; r.y += bv.y; r.z += bv.z; r.w += bv.w;
        } else if (addmode == 2) {
            float4 bv = *(const float4*)(addp + (size_t)(orow0 + row) * addJW + jc);
            r.x += bv.x; r.y += bv.y; r.z += bv.z; r.w += bv.w;
        }
        *(float4*)(outp + (size_t)(orow0 + row) * JW + jc) = r;
    }
}

// ========== bf16 staging (plain cached loads, XOR-swizzled LDS) ==========
__device__ __forceinline__ void stage_plain(const u16* __restrict__ Xg, u16* sX) {
    const int tid = threadIdx.x;
#pragma unroll
    for (int p = 0; p < 16; ++p) {
        const int chunk = p * 256 + tid;
        const int row = chunk >> 6, cb16 = chunk & 63;
        const int src = row * 1024 + cb16 * 16;
        const int dst = src ^ ((row & 7) << 4);
        *(float4*)((char*)sX + dst) = *(const float4*)((const char*)Xg + src);
    }
}

// ========== one 64-col MFMA tile, K=512, accumulating into acc[4] ==========
__device__ __forceinline__ void mfma_tile(const u16* sX, const u16* __restrict__ Wg,
                                          f32x4 acc[4]) {
    const int tid = threadIdx.x;
    const int w = tid >> 6, l15 = tid & 15, lhi = (tid & 63) >> 4;
    const int arow = w * 16 + l15;
    const char* aptr = (const char*)sX;
    const int abase = arow * 1024 + lhi * 16;
    const int aswz = (arow & 7) << 4;
#pragma unroll 4
    for (int ks = 0; ks < 16; ++ks) {
        bf16x8 a = *(const bf16x8*)(aptr + ((abase + ks * 64) ^ aswz));
        const u16* wp = Wg + l15 * 512 + ks * 32 + lhi * 8;
        acc[0] = __builtin_amdgcn_mfma_f32_16x16x32_bf16(a, *(const bf16x8*)(wp), acc[0], 0, 0, 0);
        acc[1] = __builtin_amdgcn_mfma_f32_16x16x32_bf16(a, *(const bf16x8*)(wp + 16*512), acc[1], 0, 0, 0);
        acc[2] = __builtin_amdgcn_mfma_f32_16x16x32_bf16(a, *(const bf16x8*)(wp + 32*512), acc[2], 0, 0, 0);
        acc[3] = __builtin_amdgcn_mfma_f32_16x16x32_bf16(a, *(const bf16x8*)(wp + 48*512), acc[3], 0, 0, 0);
    }
}
__device__ __forceinline__ void zero4(f32x4 a[4]) {
    f32x4 z = {0.f, 0.f, 0.f, 0.f};
    a[0] = z; a[1] = z; a[2] = z; a[3] = z;
}

// =================== upfront: all static data + initial state ===============
__global__ __launch_bounds__(256)
void k_upfront(const int* __restrict__ inp, const float* __restrict__ hid,
               const float* __restrict__ ctxin, const float* __restrict__ init_att,
               const float* __restrict__ embW,
               const float* __restrict__ W_ih0, const float* __restrict__ b_ih0,
               const float* __restrict__ W_hh0, const float* __restrict__ W_hh1,
               const float* __restrict__ W_ih1, const float* __restrict__ W_q,
               const float* __restrict__ W_read, const float* __restrict__ b_read,
               const float* __restrict__ W_pre, const float* __restrict__ b_pre,
               float* __restrict__ wsf)
{
    __shared__ float lds_x[4096], lds_w[4096];
    u16* wsu = (u16*)wsf;
    const int jid = blockIdx.x, tid = threadIdx.x, rl = tid >> 2;
    if (jid < 768) {
        const int mt = jid / 24, jt = jid % 24, j0 = jt << 6;
        const int idx = inp[mt * 64 + rl];
        gemm64(embW + (size_t)idx * 512, W_ih0 + (size_t)(j0 + rl) * 1024,
               0, 8, lds_x, lds_w, wsf + OFF_EGI, 1536, mt << 6, j0, b_ih0, 1, 0);
    } else if (jid < 1024) {
        const int r = jid - 768, mt = r >> 3, jt = r & 7, j0 = jt << 6;
        const int idx = inp[mt * 64 + rl];
        gemm64(embW + (size_t)idx * 512, W_read + (size_t)(j0 + rl) * 1536,
               0, 8, lds_x, lds_w, wsf + OFF_EREAD, 512, mt << 6, j0, b_read, 1, 0);
    } else if (jid < 2048) {
        const int r = jid - 1024, mt = r >> 3, jt = r & 7, j0 = jt << 6;
        const int m = (mt << 6) + rl, b = m >> 7, s = m & 127;
        gemm64(ctxin + (size_t)((s << 6) + b) * 512, W_pre + (size_t)(j0 + rl) * 512,
               0, 8, lds_x, lds_w, wsf + OFF_ATTPRE, 512, mt << 6, j0, b_pre, 1, 0);
    } else if (jid < 2272) {
        const int w = jid - 2048;
        if (w < 48) {
            for (int i = 0; i < 64; ++i) {
                int e = w * 16384 + i * 256 + tid;
                int j = e >> 9, k = e & 511;
                wsu[UB_WIH0C + e] = f2b(W_ih0[(size_t)j * 1024 + 512 + k]);
            }
        } else if (w < 96) {
            for (int i = 0; i < 64; ++i) {
                int e = (w - 48) * 16384 + i * 256 + tid;
                wsu[UB_WHH0 + e] = f2b(W_hh0[e]);
            }
        } else if (w < 144) {
            for (int i = 0; i < 64; ++i) {
                int e = (w - 96) * 16384 + i * 256 + tid;
                wsu[UB_WHH1 + e] = f2b(W_hh1[e]);
            }
        } else if (w < 192) {
            for (int i = 0; i < 64; ++i) {
                int e = (w - 144) * 16384 + i * 256 + tid;
                wsu[UB_WIH1 + e] = f2b(W_ih1[e]);
            }
        } else if (w < 208) {
            for (int i = 0; i < 64; ++i) {
                int e = (w - 192) * 16384 + i * 256 + tid;
                int j = e >> 9, k = e & 511;
                wsu[UB_WRO + e] = f2b(W_read[(size_t)j * 1536 + 512 + k]);
            }
        } else {
            for (int i = 0; i < 64; ++i) {
                int e = (w - 208) * 16384 + i * 256 + tid;
                int j = e >> 9, k = e & 511;
                wsu[UB_WRC + e] = f2b(W_read[(size_t)j * 1536 + 1024 + k]);
            }
        }
    } else if (jid < 2528) {
        // ctxT bf16 [b][s][e]
        const int w2 = jid - 2272;
        for (int rr = 0; rr < 32; ++rr) {
            const int r = w2 * 32 + rr;
            const int b = r >> 7, s = r & 127;
            const float* src = ctxin + ((size_t)s * 64 + b) * 512;
#pragma unroll
            for (int h = 0; h < 2; ++h) {
                int e = h * 256 + tid;
                wsu[UB_CTXT + (size_t)r * 512 + e] = f2b(src[e]);
            }
        }
    } else if (jid < 2544) {
        const int w3 = jid - 2528;
        for (int i = 0; i < 64; ++i) {
            int e = w3 * 16384 + i * 256 + tid;
            wsu[UB_WQ + e] = f2b(W_q[e]);
        }
    } else {
        // initial bf16 states into rotation slot 32 (plain stores: dispatch
        // boundary makes them coherent for k_loop)
        const int job = jid - 2544;
        const float* src = job == 0 ? hid : (job == 1 ? hid + 32768 : init_att);
        u16* dst = wsu + (size_t)(job == 0 ? ROT_H0B : (job == 1 ? ROT_H1B : ROT_CTXB))
                 + (size_t)32 * 32768;
        for (int i = 0; i < 128; ++i) {
            int e = i * 256 + tid;
            dst[e] = f2b(src[e]);
        }
    }
}

// =================== persistent loop kernel (88 blocks) ===================
__global__ __launch_bounds__(256)
void k_loop(const float* __restrict__ b_hh0, const float* __restrict__ b_ih1,
            const float* __restrict__ b_hh1, const float* __restrict__ hid,
            const float* __restrict__ maskp, const float* __restrict__ w_v,
            const float* __restrict__ W_copy, const float* __restrict__ b_copy,
            float* __restrict__ wsf, float* __restrict__ dout)
{
    __shared__ u16 sX[32768];   // 64KB staging / scratch
    u16* wsu = (u16*)wsf;
    const int blk = blockIdx.x, tid = threadIdx.x;
    const int w = tid >> 6, l15 = tid & 15, lhi = (tid & 63) >> 4;

    if (blk < 8) {
        // ================= A: layer-0 gates -> h0[t] =================
        const int j = blk;
        float hp[4][4];   // f32 h0 blend state, cols j*64.., lives in regs
#pragma unroll
        for (int cb = 0; cb < 4; ++cb)
#pragma unroll
            for (int r = 0; r < 4; ++r)
                hp[cb][r] = hid[(w * 16 + lhi * 4 + r) * 512 + j * 64 + cb * 16 + l15];

        for (int t = 0; t < 32; ++t) {
            const size_t slot = t, slotp = (t == 0) ? 32 : (size_t)(t - 1);
            if (t > 0) {
                bar_wait(cptr(wsf, t - 1, PH_A), 8);
                bar_wait(cptr(wsf, t - 1, PH_C), 64);
            }
            stage_plain(wsu + ROT_CTXB + slotp * 32768, sX);
            __syncthreads();
            f32x4 ar[4], az[4], an[4], ah[4];
            zero4(ar); zero4(az); zero4(an); zero4(ah);
            mfma_tile(sX, wsu + UB_WIH0C + (size_t)(j * 64) * 512, ar);
            mfma_tile(sX, wsu + UB_WIH0C + (size_t)(512 + j * 64) * 512, az);
            mfma_tile(sX, wsu + UB_WIH0C + (size_t)(1024 + j * 64) * 512, an);
            __syncthreads();
            stage_plain(wsu + ROT_H0B + slotp * 32768, sX);
            __syncthreads();
            mfma_tile(sX, wsu + UB_WHH0 + (size_t)(j * 64) * 512, ar);
            mfma_tile(sX, wsu + UB_WHH0 + (size_t)(512 + j * 64) * 512, az);
            mfma_tile(sX, wsu + UB_WHH0 + (size_t)(1024 + j * 64) * 512, ah);
            __syncthreads();
            const float* EG = wsf + OFF_EGI + (size_t)t * 98304;
            u16* tile = sX;
#pragma unroll
            for (int cb = 0; cb < 4; ++cb) {
                const int lc = cb * 16 + l15, gc = j * 64 + lc;
                const float brr = b_hh0[gc], bzz = b_hh0[512 + gc], bnn = b_hh0[1024 + gc];
#pragma unroll
                for (int r = 0; r < 4; ++r) {
                    const int row = w * 16 + lhi * 4 + r;
                    const float* eg = EG + (size_t)row * 1536;
                    float ir = ar[cb][r] + eg[gc];
                    float iz = az[cb][r] + eg[512 + gc];
                    float inn = an[cb][r] + eg[1024 + gc];
                    float hn = ah[cb][r] + bnn;
                    float rr = sigm(ir + brr), zz = sigm(iz + bzz);
                    float nn = tanh_(inn + rr * hn);
                    float v = (1.f - zz) * nn + zz * hp[cb][r];
                    hp[cb][r] = v;
                    tile[row * 64 + lc] = f2b(v);
                    if (t == 31) dout[OO_HID + row * 512 + gc] = v;
                }
            }
            __syncthreads();
            {
                u16* dst = wsu + ROT_H0B + slot * 32768 + j * 64;
#pragma unroll
                for (int i = 0; i < 4; ++i) {
                    int e = i * 256 + tid, row = e >> 4, c = e & 15;
                    sta8(dst + (size_t)row * 512 + c * 4, *(const u64*)(tile + row * 64 + c * 4));
                }
            }
            bar_arrive(cptr(wsf, t, PH_A));
        }
    } else if (blk < 16) {
        // ================= B: layer-1 gates -> h1/out[t] =================
        const int j = blk - 8;
        float hp[4][4];
#pragma unroll
        for (int cb = 0; cb < 4; ++cb)
#pragma unroll
            for (int r = 0; r < 4; ++r)
                hp[cb][r] = hid[32768 + (w * 16 + lhi * 4 + r) * 512 + j * 64 + cb * 16 + l15];

        for (int t = 0; t < 32; ++t) {
            const size_t slot = t, slotp = (t == 0) ? 32 : (size_t)(t - 1);
            bar_wait(cptr(wsf, t, PH_A), 8);
            if (t > 0) bar_wait(cptr(wsf, t - 1, PH_B), 8);
            stage_plain(wsu + ROT_H0B + slot * 32768, sX);
            __syncthreads();
            f32x4 ar[4], az[4], an[4], ah[4];
            zero4(ar); zero4(az); zero4(an); zero4(ah);
            mfma_tile(sX, wsu + UB_WIH1 + (size_t)(j * 64) * 512, ar);
            mfma_tile(sX, wsu + UB_WIH1 + (size_t)(512 + j * 64) * 512, az);
            mfma_tile(sX, wsu + UB_WIH1 + (size_t)(1024 + j * 64) * 512, an);
            __syncthreads();
            stage_plain(wsu + ROT_H1B + slotp * 32768, sX);
            __syncthreads();
            mfma_tile(sX, wsu + UB_WHH1 + (size_t)(j * 64) * 512, ar);
            mfma_tile(sX, wsu + UB_WHH1 + (size_t)(512 + j * 64) * 512, az);
            mfma_tile(sX, wsu + UB_WHH1 + (size_t)(1024 + j * 64) * 512, ah);
            __syncthreads();
            u16* tile = sX;
#pragma unroll
            for (int cb = 0; cb < 4; ++cb) {
                const int lc = cb * 16 + l15, gc = j * 64 + lc;
                const float bir = b_ih1[gc] + b_hh1[gc];
                const float biz = b_ih1[512 + gc] + b_hh1[512 + gc];
                const float bin_ = b_ih1[1024 + gc];
                const float bhn = b_hh1[1024 + gc];
#pragma unroll
                for (int r = 0; r < 4; ++r) {
                    const int row = w * 16 + lhi * 4 + r;
                    float rr = sigm(ar[cb][r] + bir);
                    float zz = sigm(az[cb][r] + biz);
                    float nn = tanh_(an[cb][r] + bin_ + rr * (ah[cb][r] + bhn));
                    float v = (1.f - zz) * nn + zz * hp[cb][r];
                    hp[cb][r] = v;
                    tile[row * 64 + lc] = f2b(v);
                    if (t == 31) dout[OO_HID + 32768 + row * 512 + gc] = v;
                }
            }
            __syncthreads();
            {
                u16* dst = wsu + ROT_H1B + slot * 32768 + j * 64;
#pragma unroll
                for (int i = 0; i < 4; ++i) {
                    int e = i * 256 + tid, row = e >> 4, c = e & 15;
                    sta8(dst + (size_t)row * 512 + c * 4, *(const u64*)(tile + row * 64 + c * 4));
                }
            }
            bar_arrive(cptr(wsf, t, PH_B));
        }
    } else if (blk < 80) {
        // ================= C: per-b attention =================
        const int b = blk - 16;
        float* sf = (float*)sX;
        float* s_out = sf;            // 512
        float* s_q   = sf + 512;      // 512
        float* s_e   = sf + 1024;     // 128
        float* s_at  = sf + 1152;     // 128
        float* s_ctx = sf + 1280;     // 512
        float* s_red = sf + 1792;     // 256

        for (int t = 0; t < 32; ++t) {
            const size_t slot = t;
            bar_wait(cptr(wsf, t, PH_B), 8);
            {   // out[b] = h1[t][b] (bf16, fresh plain read)
                const u16* ob = wsu + ROT_H1B + slot * 32768 + b * 512;
                const int c0 = tid * 2;
                unsigned pv = *(const unsigned*)(ob + c0);
                s_out[c0] = b2f(pv & 0xffffu);
                s_out[c0 + 1] = b2f(pv >> 16);
            }
            __syncthreads();
            {   // q = out @ W_q^T (bf16 static weights)
                const u16* wq0 = wsu + UB_WQ + (size_t)tid * 512;
                const u16* wq1 = wq0 + (size_t)256 * 512;
                float q0 = 0.f, q1 = 0.f;
#pragma unroll 4
                for (int k = 0; k < 512; k += 4) {
                    float4 ov = *(const float4*)(s_out + k);
                    u64 a0 = *(const u64*)(wq0 + k);
                    u64 a1 = *(const u64*)(wq1 + k);
                    q0 += ov.x * b2f((unsigned)(a0 & 0xffff)) + ov.y * b2f((unsigned)((a0 >> 16) & 0xffff))
                        + ov.z * b2f((unsigned)((a0 >> 32) & 0xffff)) + ov.w * b2f((unsigned)(a0 >> 48));
                    q1 += ov.x * b2f((unsigned)(a1 & 0xffff)) + ov.y * b2f((unsigned)((a1 >> 16) & 0xffff))
                        + ov.z * b2f((unsigned)((a1 >> 32) & 0xffff)) + ov.w * b2f((unsigned)(a1 >> 48));
                }
                s_q[tid] = q0; s_q[tid + 256] = q1;
            }
            __syncthreads();
            {   // energy[s] = w_v . tanh(pre + q)
                const int wid = tid >> 6, lane = tid & 63;
                for (int s = wid; s < 128; s += 4) {
                    const float* pre = wsf + OFF_ATTPRE + ((size_t)b * 128 + s) * 512;
                    float acc = 0.f;
#pragma unroll
                    for (int i = 0; i < 8; ++i) {
                        const int a = lane + (i << 6);
                        acc += tanh_(pre[a] + s_q[a]) * w_v[a];
                    }
#pragma unroll
                    for (int d2 = 1; d2 < 64; d2 <<= 1) acc += __shfl_xor(acc, d2, 64);
                    if (lane == 0)
                        s_e[s] = (maskp[b * 128 + s] > 0.5f) ? -3.0e38f : acc;
                }
            }
            __syncthreads();
            if (tid < 64) {   // softmax over S=128
                float e0 = s_e[tid], e1 = s_e[tid + 64];
                float mx = fmaxf(e0, e1);
#pragma unroll
                for (int d2 = 1; d2 < 64; d2 <<= 1) mx = fmaxf(mx, __shfl_xor(mx, d2, 64));
                float x0 = __expf(e0 - mx), x1 = __expf(e1 - mx);
                float sm = x0 + x1;
#pragma unroll
                for (int d2 = 1; d2 < 64; d2 <<= 1) sm += __shfl_xor(sm, d2, 64);
                float inv = 1.f / sm;
                x0 *= inv; x1 *= inv;
                s_at[tid] = x0; s_at[tid + 64] = x1;
                float* co = dout + OO_C + ((size_t)t * 64 + b) * 128;
                co[tid] = x0; co[tid + 64] = x1;
                if (t == 31) {
                    dout[OO_AL + b * 128 + tid] = x0;
                    dout[OO_AL + b * 128 + tid + 64] = x1;
                }
            }
            __syncthreads();
            {   // new_ctx = attn @ ctx; publish ctxb[t]
                const int e0 = tid * 2;
                const u16* ct = wsu + UB_CTXT + (size_t)b * 65536 + e0;
                float a0 = 0.f, a1 = 0.f;
#pragma unroll 4
                for (int s = 0; s < 128; ++s) {
                    float at = s_at[s];
                    unsigned pv = *(const unsigned*)(ct + s * 512);
                    a0 = fmaf(at, b2f(pv & 0xffffu), a0);
                    a1 = fmaf(at, b2f(pv >> 16), a1);
                }
                s_ctx[e0] = a0; s_ctx[e0 + 1] = a1;
                sta4(wsu + ROT_CTXB + slot * 32768 + b * 512 + e0,
                     (unsigned)f2b(a0) | ((unsigned)f2b(a1) << 16));
                if (t == 31) {
                    dout[OO_CTXF + b * 512 + e0] = a0;
                    dout[OO_CTXF + b * 512 + e0 + 1] = a1;
                }
            }
            __syncthreads();
            {   // copy gate
                float part = 0.f;
                for (int i2 = tid; i2 < 512; i2 += 256)
                    part += s_out[i2] * W_copy[i2] + s_ctx[i2] * W_copy[512 + i2];
                s_red[tid] = part;
                __syncthreads();
                for (int d2 = 128; d2 > 0; d2 >>= 1) {
                    if (tid < d2) s_red[tid] += s_red[tid + d2];
                    __syncthreads();
                }
                if (tid == 0)
                    dout[OO_CP + t * 64 + b] = sigm(s_red[0] + b_copy[0]);
            }
            bar_arrive(cptr(wsf, t, PH_C));
        }
    } else {
        // ============ RO+maxout track (8 blocks, off critical path) ============
        const int j = blk - 80;
        for (int tp = 0; tp < 32; ++tp) {
            bar_wait(cptr(wsf, tp, PH_B), 8);
            stage_plain(wsu + ROT_H1B + (size_t)tp * 32768, sX);
            __syncthreads();
            f32x4 acc[4];
            zero4(acc);
            mfma_tile(sX, wsu + UB_WRO + (size_t)(j * 64) * 512, acc);
            bar_wait(cptr(wsf, tp, PH_C), 64);
            __syncthreads();
            stage_plain(wsu + ROT_CTXB + (size_t)tp * 32768, sX);
            __syncthreads();
            mfma_tile(sX, wsu + UB_WRC + (size_t)(j * 64) * 512, acc);
            __syncthreads();
            float* ft = (float*)sX;
            const float* ER = wsf + OFF_EREAD + (size_t)tp * 32768;
#pragma unroll
            for (int cb = 0; cb < 4; ++cb) {
                const int lc = cb * 16 + l15;
#pragma unroll
                for (int r = 0; r < 4; ++r) {
                    const int row = w * 16 + lhi * 4 + r;
                    ft[row * 64 + lc] = acc[cb][r] + ER[(size_t)row * 512 + j * 64 + lc];
                }
            }
            __syncthreads();
#pragma unroll
            for (int i = 0; i < 8; ++i) {
                int e = i * 256 + tid, row = e >> 5, c2 = e & 31;
                dout[OO_G + (size_t)tp * 16384 + row * 256 + j * 32 + c2] =
                    fmaxf(ft[row * 64 + 2 * c2], ft[row * 64 + 2 * c2 + 1]);
            }
        }
    }
}

extern "C" void kernel_launch(void* const* d_in, const int* in_sizes, int n_in,
                              void* d_out, int out_size, void* d_ws, size_t ws_size,
                              hipStream_t stream) {
    const int*   inp      = (const int*)d_in[0];
    const float* hid      = (const float*)d_in[1];
    const float* ctxin    = (const float*)d_in[2];
    const float* maskp    = (const float*)d_in[3];
    const float* init_att = (const float*)d_in[4];
    const float* embW     = (const float*)d_in[5];
    const float* W_ih0    = (const float*)d_in[6];
    const float* b_ih0    = (const float*)d_in[7];
    const float* W_hh0    = (const float*)d_in[8];
    const float* b_hh0    = (const float*)d_in[9];
    const float* W_ih1    = (const float*)d_in[10];
    const float* b_ih1    = (const float*)d_in[11];
    const float* W_hh1    = (const float*)d_in[12];
    const float* b_hh1    = (const float*)d_in[13];
    const float* W_pre    = (const float*)d_in[14];
    const float* b_pre    = (const float*)d_in[15];
    const float* W_q      = (const float*)d_in[16];
    const float* w_v      = (const float*)d_in[17];
    const float* W_copy   = (const float*)d_in[18];
    const float* b_copy   = (const float*)d_in[19];
    const float* W_read   = (const float*)d_in[20];
    const float* b_read   = (const float*)d_in[21];
    float* dout = (float*)d_out;
    float* wsf  = (float*)d_ws;

    // zero the phase counters each call
    hipMemsetAsync((char*)d_ws + (size_t)OFF_CNT * 4, 0, CNT_BYTES, stream);

    k_upfront<<<dim3(2547), dim3(256), 0, stream>>>(
        inp, hid, ctxin, init_att, embW, W_ih0, b_ih0, W_hh0, W_hh1, W_ih1, W_q,
        W_read, b_read, W_pre, b_pre, wsf);

    k_loop<<<dim3(88), dim3(256), 0, stream>>>(
        b_hh0, b_ih1, b_hh1, hid, maskp, w_v, W_copy, b_copy, wsf, dout);
}

// Round 6
// 5069.336 us; speedup vs baseline: 1.1286x; 1.1135x over previous
//
#include <hip/hip_runtime.h>

// ---------------------------------------------------------------------------
// GRU decoder w/ attention. Round 6: persistent kernel, latency-tolerant attn.
// R5 post-mortem: phase C (attention) was latency-serialized (32 serial wave
// iters for energy, 128 serial loads for ctx) and ATTPRE (16MB f32) thrashed
// L2 (500MB refetch). Now: energy = 1 thread per (s,half) fully parallel;
// ATTPRE stored bf16 (L2-resident 8MB); ctx gather wave-parallel over s;
// w_v/mask/W_copy hoisted to LDS; PH_CT arrival right after ctx publish.
// ---------------------------------------------------------------------------

typedef unsigned short u16;
typedef unsigned long long u64;
using bf16x8 = __attribute__((ext_vector_type(8))) short;
using f32x4  = __attribute__((ext_vector_type(4))) float;

// ---- f32 workspace offsets (static data, written by k_upfront) ----
#define OFF_EGI    0           // [32][64][1536] emb part of gi0 (+b_ih0)
#define OFF_EREAD  3145728     // [32][64][512]  emb part of readout (+b_read)
// f32 region [4194304, 6291456) now holds UB_PREB (bf16 attn precompute)

// ---- u16 (bf16) offsets relative to (u16*)wsf ----
#define UB_PREB    8388608     // [64*128][512] attn precompute bf16 (+b_pre)
#define UB_WIH0C   18087936    // [1536][512] W_ih0 ctx-half
#define UB_WHH0    18874368    // [1536][512]
#define UB_WHH1    19660800    // [1536][512]
#define UB_WIH1    20447232    // [1536][512]
#define UB_WRO     21233664    // [512][512]  W_read out-cols
#define UB_WRC     21495808    // [512][512]  W_read ctx-cols
#define UB_CTXT    21757952    // [64][128][512] ctx transposed bf16
#define UB_WQ      26050560    // [512][512]  W_q
// rotating bf16 state shadows: 33 slots x [64][512]; slot 32 = initial state
#define ROT_H0B    26312704
#define ROT_H1B    27394048    // h1 == out
#define ROT_CTXB   28475392    // ends 29556736 u16 (byte 59113472)

// ---- phase counters: 33 steps x 3 phases x 32 u32 ----
#define OFF_CNT    14778368    // f32 offset (byte 59113472)
#define CNT_BYTES  12672
#define PH_A   0   // h0[t] ready (8 arrivals)
#define PH_B   1   // h1/out[t] ready (8)
#define PH_CT  2   // ctx[t] published (64)

// ---- output layout (float offsets into d_out) ----
#define OO_G    0
#define OO_C    524288
#define OO_CP   786432
#define OO_HID  788480
#define OO_AL   854016
#define OO_CTXF 862208

__device__ __forceinline__ float sigm(float x) {
    return 1.0f / (1.0f + __expf(-x));
}
__device__ __forceinline__ float tanh_(float x) {
    x = fmaxf(x, -15.f);
    float e = __expf(-2.0f * x);
    return (1.0f - e) / (1.0f + e);
}
__device__ __forceinline__ u16 f2b(float x) {
    unsigned u = __float_as_uint(x);
    return (u16)((u + 0x7FFFu + ((u >> 16) & 1u)) >> 16);
}
__device__ __forceinline__ float b2f(unsigned u) {
    return __uint_as_float(u << 16);
}
__device__ __forceinline__ float bfe(bf16x8 v, int k) {
    return b2f((unsigned)(unsigned short)v[k]);
}

// ---- write-through (LLC-visible) stores; reads are PLAIN on fresh addrs ----
__device__ __forceinline__ void sta8(void* p, u64 v) {
    __hip_atomic_store((u64*)p, v, __ATOMIC_RELAXED, __HIP_MEMORY_SCOPE_AGENT);
}
__device__ __forceinline__ void sta4(void* p, unsigned v) {
    __hip_atomic_store((unsigned*)p, v, __ATOMIC_RELAXED, __HIP_MEMORY_SCOPE_AGENT);
}

// ---- phase counters ----
__device__ __forceinline__ unsigned* cptr(float* wsf, int t, int ph) {
    return (unsigned*)(wsf + OFF_CNT) + (((t * 3) + ph) << 5);
}
__device__ __forceinline__ void bar_wait(unsigned* c, unsigned tgt) {
    if (threadIdx.x == 0) {
        while (__hip_atomic_load(c, __ATOMIC_RELAXED, __HIP_MEMORY_SCOPE_AGENT) < tgt) {
            __builtin_amdgcn_s_sleep(1);
        }
    }
    __syncthreads();
}
__device__ __forceinline__ void bar_arrive(unsigned* c) {
    asm volatile("s_waitcnt vmcnt(0)" ::: "memory");  // drain write-through stores
    __syncthreads();
    if (threadIdx.x == 0)
        __hip_atomic_fetch_add(c, 1u, __ATOMIC_RELAXED, __HIP_MEMORY_SCOPE_AGENT);
}

// ========== f32 tiled GEMM (upfront only); obf!=null -> bf16-only output ====
__device__ __forceinline__ void gemm64(
    const float* __restrict__ xrow, const float* __restrict__ wrow,
    int kt0, int nkt, float* lds_x, float* lds_w,
    float* __restrict__ outp, int JW, int orow0, int j0,
    const float* __restrict__ addp, int addmode, int addJW,
    u16* __restrict__ obf)
{
    const int tid = threadIdx.x;
    const int tb4 = tid >> 4, tj4 = tid & 15;
    float acc[4][4];
#pragma unroll
    for (int a = 0; a < 4; ++a)
#pragma unroll
        for (int b = 0; b < 4; ++b) acc[a][b] = 0.f;

    for (int kt = kt0; kt < kt0 + nkt; ++kt) {
        const int kb = kt << 6;
        __syncthreads();
        {
            const int rl = tid >> 2;
#pragma unroll
            for (int i = 0; i < 4; ++i) {
                const int kk = ((tid & 3) << 4) + (i << 2);
                float4 xv = *(const float4*)(xrow + kb + kk);
                float4 wv = *(const float4*)(wrow + kb + kk);
                lds_x[(kk + 0) * 64 + rl] = xv.x;
                lds_x[(kk + 1) * 64 + rl] = xv.y;
                lds_x[(kk + 2) * 64 + rl] = xv.z;
                lds_x[(kk + 3) * 64 + rl] = xv.w;
                lds_w[(kk + 0) * 64 + rl] = wv.x;
                lds_w[(kk + 1) * 64 + rl] = wv.y;
                lds_w[(kk + 2) * 64 + rl] = wv.z;
                lds_w[(kk + 3) * 64 + rl] = wv.w;
            }
        }
        __syncthreads();
#pragma unroll 4
        for (int kk = 0; kk < 64; ++kk) {
            float4 xv = *(const float4*)(lds_x + kk * 64 + tb4 * 4);
            float4 wv = *(const float4*)(lds_w + kk * 64 + tj4 * 4);
            acc[0][0] += xv.x * wv.x; acc[0][1] += xv.x * wv.y;
            acc[0][2] += xv.x * wv.z; acc[0][3] += xv.x * wv.w;
            acc[1][0] += xv.y * wv.x; acc[1][1] += xv.y * wv.y;
            acc[1][2] += xv.y * wv.z; acc[1][3] += xv.y * wv.w;
            acc[2][0] += xv.z * wv.x; acc[2][1] += xv.z * wv.y;
            acc[2][2] += xv.z * wv.z; acc[2][3] += xv.z * wv.w;
            acc[3][0] += xv.w * wv.x; acc[3][1] += xv.w * wv.y;
            acc[3][2] += xv.w * wv.z; acc[3][3] += xv.w * wv.w;
        }
    }
#pragma unroll
    for (int ib = 0; ib < 4; ++ib) {
        const int row = tb4 * 4 + ib;
        const int jc = j0 + tj4 * 4;
        float4 r;
        r.x = acc[ib][0]; r.y = acc[ib][1]; r.z = acc[ib][2]; r.w = acc[ib][3];
        if (addmode == 1) {
            float4 bv = *(const float4*)(addp + jc);
            r.x += bv.x; r.y += bv.y; r.z += bv.z; r.w += bv.w;
        } else if (addmode == 2) {
            float4 bv = *(const float4*)(addp + (size_t)(orow0 + row) * addJW + jc);
            r.x += bv.x; r.y += bv.y; r.z += bv.z; r.w += bv.w;
        }
        if (obf) {
            u64 pv = (u64)f2b(r.x) | ((u64)f2b(r.y) << 16)
                   | ((u64)f2b(r.z) << 32) | ((u64)f2b(r.w) << 48);
            *(u64*)(obf + (size_t)(orow0 + row) * 512 + jc) = pv;
        } else {
            *(float4*)(outp + (size_t)(orow0 + row) * JW + jc) = r;
        }
    }
}

// ========== bf16 staging (plain cached loads, XOR-swizzled LDS) ==========
__device__ __forceinline__ void stage_plain(const u16* __restrict__ Xg, u16* sX) {
    const int tid = threadIdx.x;
#pragma unroll
    for (int p = 0; p < 16; ++p) {
        const int chunk = p * 256 + tid;
        const int row = chunk >> 6, cb16 = chunk & 63;
        const int src = row * 1024 + cb16 * 16;
        const int dst = src ^ ((row & 7) << 4);
        *(float4*)((char*)sX + dst) = *(const float4*)((const char*)Xg + src);
    }
}

// ========== one 64-col MFMA tile, K=512, accumulating into acc[4] ==========
__device__ __forceinline__ void mfma_tile(const u16* sX, const u16* __restrict__ Wg,
                                          f32x4 acc[4]) {
    const int tid = threadIdx.x;
    const int w = tid >> 6, l15 = tid & 15, lhi = (tid & 63) >> 4;
    const int arow = w * 16 + l15;
    const char* aptr = (const char*)sX;
    const int abase = arow * 1024 + lhi * 16;
    const int aswz = (arow & 7) << 4;
#pragma unroll 4
    for (int ks = 0; ks < 16; ++ks) {
        bf16x8 a = *(const bf16x8*)(aptr + ((abase + ks * 64) ^ aswz));
        const u16* wp = Wg + l15 * 512 + ks * 32 + lhi * 8;
        acc[0] = __builtin_amdgcn_mfma_f32_16x16x32_bf16(a, *(const bf16x8*)(wp), acc[0], 0, 0, 0);
        acc[1] = __builtin_amdgcn_mfma_f32_16x16x32_bf16(a, *(const bf16x8*)(wp + 16*512), acc[1], 0, 0, 0);
        acc[2] = __builtin_amdgcn_mfma_f32_16x16x32_bf16(a, *(const bf16x8*)(wp + 32*512), acc[2], 0, 0, 0);
        acc[3] = __builtin_amdgcn_mfma_f32_16x16x32_bf16(a, *(const bf16x8*)(wp + 48*512), acc[3], 0, 0, 0);
    }
}
__device__ __forceinline__ void zero4(f32x4 a[4]) {
    f32x4 z = {0.f, 0.f, 0.f, 0.f};
    a[0] = z; a[1] = z; a[2] = z; a[3] = z;
}

// =================== upfront: all static data + initial state ===============
__global__ __launch_bounds__(256)
void k_upfront(const int* __restrict__ inp, const float* __restrict__ hid,
               const float* __restrict__ ctxin, const float* __restrict__ init_att,
               const float* __restrict__ embW,
               const float* __restrict__ W_ih0, const float* __restrict__ b_ih0,
               const float* __restrict__ W_hh0, const float* __restrict__ W_hh1,
               const float* __restrict__ W_ih1, const float* __restrict__ W_q,
               const float* __restrict__ W_read, const float* __restrict__ b_read,
               const float* __restrict__ W_pre, const float* __restrict__ b_pre,
               float* __restrict__ wsf)
{
    __shared__ float lds_x[4096], lds_w[4096];
    u16* wsu = (u16*)wsf;
    const int jid = blockIdx.x, tid = threadIdx.x, rl = tid >> 2;
    if (jid < 768) {
        const int mt = jid / 24, jt = jid % 24, j0 = jt << 6;
        const int idx = inp[mt * 64 + rl];
        gemm64(embW + (size_t)idx * 512, W_ih0 + (size_t)(j0 + rl) * 1024,
               0, 8, lds_x, lds_w, wsf + OFF_EGI, 1536, mt << 6, j0, b_ih0, 1, 0, nullptr);
    } else if (jid < 1024) {
        const int r = jid - 768, mt = r >> 3, jt = r & 7, j0 = jt << 6;
        const int idx = inp[mt * 64 + rl];
        gemm64(embW + (size_t)idx * 512, W_read + (size_t)(j0 + rl) * 1536,
               0, 8, lds_x, lds_w, wsf + OFF_EREAD, 512, mt << 6, j0, b_read, 1, 0, nullptr);
    } else if (jid < 2048) {
        const int r = jid - 1024, mt = r >> 3, jt = r & 7, j0 = jt << 6;
        const int m = (mt << 6) + rl, b = m >> 7, s = m & 127;
        gemm64(ctxin + (size_t)((s << 6) + b) * 512, W_pre + (size_t)(j0 + rl) * 512,
               0, 8, lds_x, lds_w, nullptr, 512, mt << 6, j0, b_pre, 1, 0,
               wsu + UB_PREB);
    } else if (jid < 2272) {
        const int w = jid - 2048;
        if (w < 48) {
            for (int i = 0; i < 64; ++i) {
                int e = w * 16384 + i * 256 + tid;
                int j = e >> 9, k = e & 511;
                wsu[UB_WIH0C + e] = f2b(W_ih0[(size_t)j * 1024 + 512 + k]);
            }
        } else if (w < 96) {
            for (int i = 0; i < 64; ++i) {
                int e = (w - 48) * 16384 + i * 256 + tid;
                wsu[UB_WHH0 + e] = f2b(W_hh0[e]);
            }
        } else if (w < 144) {
            for (int i = 0; i < 64; ++i) {
                int e = (w - 96) * 16384 + i * 256 + tid;
                wsu[UB_WHH1 + e] = f2b(W_hh1[e]);
            }
        } else if (w < 192) {
            for (int i = 0; i < 64; ++i) {
                int e = (w - 144) * 16384 + i * 256 + tid;
                wsu[UB_WIH1 + e] = f2b(W_ih1[e]);
            }
        } else if (w < 208) {
            for (int i = 0; i < 64; ++i) {
                int e = (w - 192) * 16384 + i * 256 + tid;
                int j = e >> 9, k = e & 511;
                wsu[UB_WRO + e] = f2b(W_read[(size_t)j * 1536 + 512 + k]);
            }
        } else {
            for (int i = 0; i < 64; ++i) {
                int e = (w - 208) * 16384 + i * 256 + tid;
                int j = e >> 9, k = e & 511;
                wsu[UB_WRC + e] = f2b(W_read[(size_t)j * 1536 + 1024 + k]);
            }
        }
    } else if (jid < 2528) {
        // ctxT bf16 [b][s][e]
        const int w2 = jid - 2272;
        for (int rr = 0; rr < 32; ++rr) {
            const int r = w2 * 32 + rr;
            const int b = r >> 7, s = r & 127;
            const float* src = ctxin + ((size_t)s * 64 + b) * 512;
#pragma unroll
            for (int h = 0; h < 2; ++h) {
                int e = h * 256 + tid;
                wsu[UB_CTXT + (size_t)r * 512 + e] = f2b(src[e]);
            }
        }
    } else if (jid < 2544) {
        const int w3 = jid - 2528;
        for (int i = 0; i < 64; ++i) {
            int e = w3 * 16384 + i * 256 + tid;
            wsu[UB_WQ + e] = f2b(W_q[e]);
        }
    } else {
        // initial bf16 states into rotation slot 32
        const int job = jid - 2544;
        const float* src = job == 0 ? hid : (job == 1 ? hid + 32768 : init_att);
        u16* dst = wsu + (size_t)(job == 0 ? ROT_H0B : (job == 1 ? ROT_H1B : ROT_CTXB))
                 + (size_t)32 * 32768;
        for (int i = 0; i < 128; ++i) {
            int e = i * 256 + tid;
            dst[e] = f2b(src[e]);
        }
    }
}

// =================== persistent loop kernel (88 blocks) ===================
__global__ __launch_bounds__(256)
void k_loop(const float* __restrict__ b_hh0, const float* __restrict__ b_ih1,
            const float* __restrict__ b_hh1, const float* __restrict__ hid,
            const float* __restrict__ maskp, const float* __restrict__ w_v,
            const float* __restrict__ W_copy, const float* __restrict__ b_copy,
            float* __restrict__ wsf, float* __restrict__ dout)
{
    __shared__ u16 sX[32768];   // 64KB staging / scratch
    u16* wsu = (u16*)wsf;
    const int blk = blockIdx.x, tid = threadIdx.x;
    const int w = tid >> 6, l15 = tid & 15, lhi = (tid & 63) >> 4;

    if (blk < 8) {
        // ================= A: layer-0 gates -> h0[t] =================
        const int j = blk;
        float hp[4][4];
#pragma unroll
        for (int cb = 0; cb < 4; ++cb)
#pragma unroll
            for (int r = 0; r < 4; ++r)
                hp[cb][r] = hid[(w * 16 + lhi * 4 + r) * 512 + j * 64 + cb * 16 + l15];

        for (int t = 0; t < 32; ++t) {
            const size_t slot = t, slotp = (t == 0) ? 32 : (size_t)(t - 1);
            if (t > 0) {
                bar_wait(cptr(wsf, t - 1, PH_A), 8);
                bar_wait(cptr(wsf, t - 1, PH_CT), 64);
            }
            stage_plain(wsu + ROT_CTXB + slotp * 32768, sX);
            __syncthreads();
            f32x4 ar[4], az[4], an[4], ah[4];
            zero4(ar); zero4(az); zero4(an); zero4(ah);
            mfma_tile(sX, wsu + UB_WIH0C + (size_t)(j * 64) * 512, ar);
            mfma_tile(sX, wsu + UB_WIH0C + (size_t)(512 + j * 64) * 512, az);
            mfma_tile(sX, wsu + UB_WIH0C + (size_t)(1024 + j * 64) * 512, an);
            __syncthreads();
            stage_plain(wsu + ROT_H0B + slotp * 32768, sX);
            __syncthreads();
            mfma_tile(sX, wsu + UB_WHH0 + (size_t)(j * 64) * 512, ar);
            mfma_tile(sX, wsu + UB_WHH0 + (size_t)(512 + j * 64) * 512, az);
            mfma_tile(sX, wsu + UB_WHH0 + (size_t)(1024 + j * 64) * 512, ah);
            __syncthreads();
            const float* EG = wsf + OFF_EGI + (size_t)t * 98304;
            u16* tile = sX;
#pragma unroll
            for (int cb = 0; cb < 4; ++cb) {
                const int lc = cb * 16 + l15, gc = j * 64 + lc;
                const float brr = b_hh0[gc], bzz = b_hh0[512 + gc], bnn = b_hh0[1024 + gc];
#pragma unroll
                for (int r = 0; r < 4; ++r) {
                    const int row = w * 16 + lhi * 4 + r;
                    const float* eg = EG + (size_t)row * 1536;
                    float ir = ar[cb][r] + eg[gc];
                    float iz = az[cb][r] + eg[512 + gc];
                    float inn = an[cb][r] + eg[1024 + gc];
                    float hn = ah[cb][r] + bnn;
                    float rr = sigm(ir + brr), zz = sigm(iz + bzz);
                    float nn = tanh_(inn + rr * hn);
                    float v = (1.f - zz) * nn + zz * hp[cb][r];
                    hp[cb][r] = v;
                    tile[row * 64 + lc] = f2b(v);
                    if (t == 31) dout[OO_HID + row * 512 + gc] = v;
                }
            }
            __syncthreads();
            {
                u16* dst = wsu + ROT_H0B + slot * 32768 + j * 64;
#pragma unroll
                for (int i = 0; i < 4; ++i) {
                    int e = i * 256 + tid, row = e >> 4, c = e & 15;
                    sta8(dst + (size_t)row * 512 + c * 4, *(const u64*)(tile + row * 64 + c * 4));
                }
            }
            bar_arrive(cptr(wsf, t, PH_A));
        }
    } else if (blk < 16) {
        // ================= B: layer-1 gates -> h1/out[t] =================
        const int j = blk - 8;
        float hp[4][4];
#pragma unroll
        for (int cb = 0; cb < 4; ++cb)
#pragma unroll
            for (int r = 0; r < 4; ++r)
                hp[cb][r] = hid[32768 + (w * 16 + lhi * 4 + r) * 512 + j * 64 + cb * 16 + l15];

        for (int t = 0; t < 32; ++t) {
            const size_t slot = t, slotp = (t == 0) ? 32 : (size_t)(t - 1);
            bar_wait(cptr(wsf, t, PH_A), 8);
            if (t > 0) bar_wait(cptr(wsf, t - 1, PH_B), 8);
            stage_plain(wsu + ROT_H0B + slot * 32768, sX);
            __syncthreads();
            f32x4 ar[4], az[4], an[4], ah[4];
            zero4(ar); zero4(az); zero4(an); zero4(ah);
            mfma_tile(sX, wsu + UB_WIH1 + (size_t)(j * 64) * 512, ar);
            mfma_tile(sX, wsu + UB_WIH1 + (size_t)(512 + j * 64) * 512, az);
            mfma_tile(sX, wsu + UB_WIH1 + (size_t)(1024 + j * 64) * 512, an);
            __syncthreads();
            stage_plain(wsu + ROT_H1B + slotp * 32768, sX);
            __syncthreads();
            mfma_tile(sX, wsu + UB_WHH1 + (size_t)(j * 64) * 512, ar);
            mfma_tile(sX, wsu + UB_WHH1 + (size_t)(512 + j * 64) * 512, az);
            mfma_tile(sX, wsu + UB_WHH1 + (size_t)(1024 + j * 64) * 512, ah);
            __syncthreads();
            u16* tile = sX;
#pragma unroll
            for (int cb = 0; cb < 4; ++cb) {
                const int lc = cb * 16 + l15, gc = j * 64 + lc;
                const float bir = b_ih1[gc] + b_hh1[gc];
                const float biz = b_ih1[512 + gc] + b_hh1[512 + gc];
                const float bin_ = b_ih1[1024 + gc];
                const float bhn = b_hh1[1024 + gc];
#pragma unroll
                for (int r = 0; r < 4; ++r) {
                    const int row = w * 16 + lhi * 4 + r;
                    float rr = sigm(ar[cb][r] + bir);
                    float zz = sigm(az[cb][r] + biz);
                    float nn = tanh_(an[cb][r] + bin_ + rr * (ah[cb][r] + bhn));
                    float v = (1.f - zz) * nn + zz * hp[cb][r];
                    hp[cb][r] = v;
                    tile[row * 64 + lc] = f2b(v);
                    if (t == 31) dout[OO_HID + 32768 + row * 512 + gc] = v;
                }
            }
            __syncthreads();
            {
                u16* dst = wsu + ROT_H1B + slot * 32768 + j * 64;
#pragma unroll
                for (int i = 0; i < 4; ++i) {
                    int e = i * 256 + tid, row = e >> 4, c = e & 15;
                    sta8(dst + (size_t)row * 512 + c * 4, *(const u64*)(tile + row * 64 + c * 4));
                }
            }
            bar_arrive(cptr(wsf, t, PH_B));
        }
    } else if (blk < 80) {
        // ================= C: per-b attention (latency-tolerant) =============
        const int b = blk - 16;
        float* sf = (float*)sX;
        float* s_out  = sf;            // 512
        float* s_q    = sf + 512;      // 512
        float* s_e    = sf + 1024;     // 128
        float* s_at   = sf + 1152;     // 128
        float* s_ctx  = sf + 1280;     // 512
        float* s_red  = sf + 1792;     // 256
        float* s_part = sf + 2048;     // 256
        float* s_ctxp = sf + 2304;     // 4*512
        float* s_wv   = sf + 4352;     // 512 (persistent)
        float* s_msk  = sf + 4864;     // 128 (persistent)
        float* s_wcp  = sf + 4992;     // 1024 (persistent)

        // hoist static small vectors into LDS once
        for (int i = tid; i < 512; i += 256) s_wv[i] = w_v[i];
        for (int i = tid; i < 1024; i += 256) s_wcp[i] = W_copy[i];
        if (tid < 128) s_msk[tid] = (maskp[b * 128 + tid] > 0.5f) ? -3.0e38f : 0.0f;
        __syncthreads();

        for (int t = 0; t < 32; ++t) {
            const size_t slot = t;
            bar_wait(cptr(wsf, t, PH_B), 8);
            {   // out[b] = h1[t][b]
                const u16* ob = wsu + ROT_H1B + slot * 32768 + b * 512;
                const int c0 = tid * 2;
                unsigned pv = *(const unsigned*)(ob + c0);
                s_out[c0] = b2f(pv & 0xffffu);
                s_out[c0 + 1] = b2f(pv >> 16);
            }
            __syncthreads();
            {   // q = out @ W_q^T : thread owns a-cols tid and tid+256
                const u16* wq0 = wsu + UB_WQ + (size_t)tid * 512;
                const u16* wq1 = wq0 + (size_t)256 * 512;
                float q0 = 0.f, q1 = 0.f;
#pragma unroll 8
                for (int i = 0; i < 64; ++i) {
                    bf16x8 w0 = *(const bf16x8*)(wq0 + i * 8);
                    bf16x8 w1 = *(const bf16x8*)(wq1 + i * 8);
#pragma unroll
                    for (int k2 = 0; k2 < 8; ++k2) {
                        float ov = s_out[i * 8 + k2];
                        q0 += ov * bfe(w0, k2);
                        q1 += ov * bfe(w1, k2);
                    }
                }
                s_q[tid] = q0; s_q[tid + 256] = q1;
            }
            __syncthreads();
            {   // energy: thread = (s, half); 256 contiguous bf16 each
                const int s = tid >> 1, sh = tid & 1;
                const u16* prep = wsu + UB_PREB + (((size_t)b * 128 + s) << 9) + (sh << 8);
                float part = 0.f;
#pragma unroll 4
                for (int i = 0; i < 32; ++i) {
                    bf16x8 v = *(const bf16x8*)(prep + i * 8);
#pragma unroll
                    for (int k2 = 0; k2 < 8; ++k2) {
                        const int a = (sh << 8) + i * 8 + k2;
                        part += tanh_(bfe(v, k2) + s_q[a]) * s_wv[a];
                    }
                }
                s_part[tid] = part;
            }
            __syncthreads();
            if (tid < 128) s_e[tid] = s_part[tid * 2] + s_part[tid * 2 + 1] + s_msk[tid];
            __syncthreads();
            if (tid < 64) {   // softmax over S=128
                float e0 = s_e[tid], e1 = s_e[tid + 64];
                float mx = fmaxf(e0, e1);
#pragma unroll
                for (int d2 = 1; d2 < 64; d2 <<= 1) mx = fmaxf(mx, __shfl_xor(mx, d2, 64));
                float x0 = __expf(e0 - mx), x1 = __expf(e1 - mx);
                float sm = x0 + x1;
#pragma unroll
                for (int d2 = 1; d2 < 64; d2 <<= 1) sm += __shfl_xor(sm, d2, 64);
                float inv = 1.f / sm;
                x0 *= inv; x1 *= inv;
                s_at[tid] = x0; s_at[tid + 64] = x1;
                float* co = dout + OO_C + ((size_t)t * 64 + b) * 128;
                co[tid] = x0; co[tid + 64] = x1;
                if (t == 31) {
                    dout[OO_AL + b * 128 + tid] = x0;
                    dout[OO_AL + b * 128 + tid + 64] = x1;
                }
            }
            __syncthreads();
            {   // ctx gather: wave-parallel over s; lane owns 8 contiguous e
                const u16* ct = wsu + UB_CTXT + (size_t)b * 65536;
                const int ln = tid & 63;
                float ac[8] = {0.f,0.f,0.f,0.f,0.f,0.f,0.f,0.f};
#pragma unroll 4
                for (int si = 0; si < 32; ++si) {
                    const int s2 = w * 32 + si;
                    const float at = s_at[s2];
                    bf16x8 v = *(const bf16x8*)(ct + (size_t)s2 * 512 + ln * 8);
#pragma unroll
                    for (int k2 = 0; k2 < 8; ++k2) ac[k2] = fmaf(at, bfe(v, k2), ac[k2]);
                }
#pragma unroll
                for (int k2 = 0; k2 < 8; ++k2) s_ctxp[w * 512 + ln * 8 + k2] = ac[k2];
            }
            __syncthreads();
            {   // combine 4 wave-partials; publish ctx
                const int e0 = tid * 2;
                float c0 = s_ctxp[e0] + s_ctxp[512 + e0] + s_ctxp[1024 + e0] + s_ctxp[1536 + e0];
                float c1 = s_ctxp[e0 + 1] + s_ctxp[512 + e0 + 1] + s_ctxp[1024 + e0 + 1] + s_ctxp[1536 + e0 + 1];
                s_ctx[e0] = c0; s_ctx[e0 + 1] = c1;
                sta4(wsu + ROT_CTXB + slot * 32768 + b * 512 + e0,
                     (unsigned)f2b(c0) | ((unsigned)f2b(c1) << 16));
                if (t == 31) {
                    dout[OO_CTXF + b * 512 + e0] = c0;
                    dout[OO_CTXF + b * 512 + e0 + 1] = c1;
                }
            }
            bar_arrive(cptr(wsf, t, PH_CT));   // A(t+1) can start now
            {   // copy gate (off critical path)
                const int i2 = tid * 2;
                float part = s_out[i2] * s_wcp[i2] + s_ctx[i2] * s_wcp[512 + i2]
                           + s_out[i2 + 1] * s_wcp[i2 + 1] + s_ctx[i2 + 1] * s_wcp[512 + i2 + 1];
                s_red[tid] = part;
                __syncthreads();
                for (int d2 = 128; d2 > 0; d2 >>= 1) {
                    if (tid < d2) s_red[tid] += s_red[tid + d2];
                    __syncthreads();
                }
                if (tid == 0)
                    dout[OO_CP + t * 64 + b] = sigm(s_red[0] + b_copy[0]);
            }
        }
    } else {
        // ============ RO+maxout track (8 blocks, off critical path) ============
        const int j = blk - 80;
        for (int tp = 0; tp < 32; ++tp) {
            bar_wait(cptr(wsf, tp, PH_B), 8);
            stage_plain(wsu + ROT_H1B + (size_t)tp * 32768, sX);
            __syncthreads();
            f32x4 acc[4];
            zero4(acc);
            mfma_tile(sX, wsu + UB_WRO + (size_t)(j * 64) * 512, acc);
            bar_wait(cptr(wsf, tp, PH_CT), 64);
            __syncthreads();
            stage_plain(wsu + ROT_CTXB + (size_t)tp * 32768, sX);
            __syncthreads();
            mfma_tile(sX, wsu + UB_WRC + (size_t)(j * 64) * 512, acc);
            __syncthreads();
            float* ft = (float*)sX;
            const float* ER = wsf + OFF_EREAD + (size_t)tp * 32768;
#pragma unroll
            for (int cb = 0; cb < 4; ++cb) {
                const int lc = cb * 16 + l15;
#pragma unroll
                for (int r = 0; r < 4; ++r) {
                    const int row = w * 16 + lhi * 4 + r;
                    ft[row * 64 + lc] = acc[cb][r] + ER[(size_t)row * 512 + j * 64 + lc];
                }
            }
            __syncthreads();
#pragma unroll
            for (int i = 0; i < 8; ++i) {
                int e = i * 256 + tid, row = e >> 5, c2 = e & 31;
                dout[OO_G + (size_t)tp * 16384 + row * 256 + j * 32 + c2] =
                    fmaxf(ft[row * 64 + 2 * c2], ft[row * 64 + 2 * c2 + 1]);
            }
        }
    }
}

extern "C" void kernel_launch(void* const* d_in, const int* in_sizes, int n_in,
                              void* d_out, int out_size, void* d_ws, size_t ws_size,
                              hipStream_t stream) {
    const int*   inp      = (const int*)d_in[0];
    const float* hid      = (const float*)d_in[1];
    const float* ctxin    = (const float*)d_in[2];
    const float* maskp    = (const float*)d_in[3];
    const float* init_att = (const float*)d_in[4];
    const float* embW     = (const float*)d_in[5];
    const float* W_ih0    = (const float*)d_in[6];
    const float* b_ih0    = (const float*)d_in[7];
    const float* W_hh0    = (const float*)d_in[8];
    const float* b_hh0    = (const float*)d_in[9];
    const float* W_ih1    = (const float*)d_in[10];
    const float* b_ih1    = (const float*)d_in[11];
    const float* W_hh1    = (const float*)d_in[12];
    const float* b_hh1    = (const float*)d_in[13];
    const float* W_pre    = (const float*)d_in[14];
    const float* b_pre    = (const float*)d_in[15];
    const float* W_q      = (const float*)d_in[16];
    const float* w_v      = (const float*)d_in[17];
    const float* W_copy   = (const float*)d_in[18];
    const float* b_copy   = (const float*)d_in[19];
    const float* W_read   = (const float*)d_in[20];
    const float* b_read   = (const float*)d_in[21];
    float* dout = (float*)d_out;
    float* wsf  = (float*)d_ws;

    // zero the phase counters each call
    hipMemsetAsync((char*)d_ws + (size_t)OFF_CNT * 4, 0, CNT_BYTES, stream);

    k_upfront<<<dim3(2547), dim3(256), 0, stream>>>(
        inp, hid, ctxin, init_att, embW, W_ih0, b_ih0, W_hh0, W_hh1, W_ih1, W_q,
        W_read, b_read, W_pre, b_pre, wsf);

    k_loop<<<dim3(88), dim3(256), 0, stream>>>(
        b_hh0, b_ih1, b_hh1, hid, maskp, w_v, W_copy, b_copy, wsf, dout);
}

// Round 7
// 3099.623 us; speedup vs baseline: 1.8457x; 1.6355x over previous
//
#include <hip/hip_runtime.h>

// ---------------------------------------------------------------------------
// GRU decoder w/ attention. Round 7: persistent kernel, overlapped phases.
// R6 post-mortem: 150us/step = serialized L2-miss latency (10.6MB/step at
// 72GB/s effective, 4 waves/CU). Changes:
//  1. gh0/gh1 (hidden-half GEMMs) moved OFF the critical path: computed right
//     after PH_A/PH_B(t-1), overlapping phase C of step t-1.
//  2. mfma_tile3 merges the 3 gate tiles -> 12 outstanding weight loads per
//     k-slice (3x MLP); EGI combine-operands prefetched into registers.
//  3. PH_CT split into 8 per-group counters on separate lines, polled by 8
//     lanes in parallel (de-contends 64-way same-line atomics).
// Critical chain/step: PH_CT -> stage ctx + 3 gi0 tiles + combine -> PH_A ->
//                      stage h0 + 3 gi1 tiles + combine -> PH_B -> attention.
// ---------------------------------------------------------------------------

typedef unsigned short u16;
typedef unsigned long long u64;
using bf16x8 = __attribute__((ext_vector_type(8))) short;
using f32x4  = __attribute__((ext_vector_type(4))) float;

// ---- f32 workspace offsets ----
#define OFF_EGI    0           // [32][64][1536] emb part of gi0 (+b_ih0)
#define OFF_EREAD  3145728     // [32][64][512]  emb part of readout (+b_read)
// f32 [4194304, 6291456) = UB_PREB (bf16). Counters in free gap below.
#define OFF_CNT    6291456     // f32 offset (byte 25165824)
#define CNT_BYTES  101376      // 33 steps x 3 phases x 8 groups x 128B

// ---- u16 (bf16) offsets relative to (u16*)wsf ----
#define UB_PREB    8388608     // [64*128][512] attn precompute bf16 (+b_pre)
#define UB_WIH0C   18087936    // [1536][512] W_ih0 ctx-half
#define UB_WHH0    18874368    // [1536][512]
#define UB_WHH1    19660800    // [1536][512]
#define UB_WIH1    20447232    // [1536][512]
#define UB_WRO     21233664    // [512][512]  W_read out-cols
#define UB_WRC     21495808    // [512][512]  W_read ctx-cols
#define UB_CTXT    21757952    // [64][128][512] ctx transposed bf16
#define UB_WQ      26050560    // [512][512]  W_q
// rotating bf16 state shadows: 33 slots x [64][512]; slot 32 = initial state
#define ROT_H0B    26312704
#define ROT_H1B    27394048    // h1 == out
#define ROT_CTXB   28475392    // ends 29556736 u16 (byte 59113472)

#define PH_A   0   // h0[t] ready (8 arrivals, group 0)
#define PH_B   1   // h1/out[t] ready (8 arrivals, group 0)
#define PH_CT  2   // ctx[t] published (8 groups x 8 arrivals)

// ---- output layout (float offsets into d_out) ----
#define OO_G    0
#define OO_C    524288
#define OO_CP   786432
#define OO_HID  788480
#define OO_AL   854016
#define OO_CTXF 862208

__device__ __forceinline__ float sigm(float x) {
    return 1.0f / (1.0f + __expf(-x));
}
__device__ __forceinline__ float tanh_(float x) {
    x = fmaxf(x, -15.f);
    float e = __expf(-2.0f * x);
    return (1.0f - e) / (1.0f + e);
}
__device__ __forceinline__ u16 f2b(float x) {
    unsigned u = __float_as_uint(x);
    return (u16)((u + 0x7FFFu + ((u >> 16) & 1u)) >> 16);
}
__device__ __forceinline__ float b2f(unsigned u) {
    return __uint_as_float(u << 16);
}
__device__ __forceinline__ float bfe(bf16x8 v, int k) {
    return b2f((unsigned)(unsigned short)v[k]);
}

// ---- write-through (LLC-visible) stores; reads are PLAIN on fresh addrs ----
__device__ __forceinline__ void sta8(void* p, u64 v) {
    __hip_atomic_store((u64*)p, v, __ATOMIC_RELAXED, __HIP_MEMORY_SCOPE_AGENT);
}
__device__ __forceinline__ void sta4(void* p, unsigned v) {
    __hip_atomic_store((unsigned*)p, v, __ATOMIC_RELAXED, __HIP_MEMORY_SCOPE_AGENT);
}

// ---- phase counters: each (t,ph,group) on its own 128B line ----
__device__ __forceinline__ unsigned* cptr(float* wsf, int t, int ph, int g) {
    return (unsigned*)(wsf + OFF_CNT) + ((((t * 3) + ph) * 8 + g) << 5);
}
__device__ __forceinline__ void bar_wait1(unsigned* c, unsigned tgt) {
    if (threadIdx.x == 0) {
        while (__hip_atomic_load(c, __ATOMIC_RELAXED, __HIP_MEMORY_SCOPE_AGENT) < tgt)
            __builtin_amdgcn_s_sleep(1);
    }
    __syncthreads();
}
// 8 lanes poll 8 group counters in parallel
__device__ __forceinline__ void bar_wait8(unsigned* base, unsigned tgt) {
    if (threadIdx.x < 8) {
        unsigned* c = base + (threadIdx.x << 5);
        while (__hip_atomic_load(c, __ATOMIC_RELAXED, __HIP_MEMORY_SCOPE_AGENT) < tgt)
            __builtin_amdgcn_s_sleep(1);
    }
    __syncthreads();
}
__device__ __forceinline__ void bar_arrive(unsigned* c) {
    asm volatile("s_waitcnt vmcnt(0)" ::: "memory");  // drain write-through stores
    __syncthreads();
    if (threadIdx.x == 0)
        __hip_atomic_fetch_add(c, 1u, __ATOMIC_RELAXED, __HIP_MEMORY_SCOPE_AGENT);
}

// ========== f32 tiled GEMM (upfront only); obf!=null -> bf16-only output ====
__device__ __forceinline__ void gemm64(
    const float* __restrict__ xrow, const float* __restrict__ wrow,
    int kt0, int nkt, float* lds_x, float* lds_w,
    float* __restrict__ outp, int JW, int orow0, int j0,
    const float* __restrict__ addp, int addmode, int addJW,
    u16* __restrict__ obf)
{
    const int tid = threadIdx.x;
    const int tb4 = tid >> 4, tj4 = tid & 15;
    float acc[4][4];
#pragma unroll
    for (int a = 0; a < 4; ++a)
#pragma unroll
        for (int b = 0; b < 4; ++b) acc[a][b] = 0.f;

    for (int kt = kt0; kt < kt0 + nkt; ++kt) {
        const int kb = kt << 6;
        __syncthreads();
        {
            const int rl = tid >> 2;
#pragma unroll
            for (int i = 0; i < 4; ++i) {
                const int kk = ((tid & 3) << 4) + (i << 2);
                float4 xv = *(const float4*)(xrow + kb + kk);
                float4 wv = *(const float4*)(wrow + kb + kk);
                lds_x[(kk + 0) * 64 + rl] = xv.x;
                lds_x[(kk + 1) * 64 + rl] = xv.y;
                lds_x[(kk + 2) * 64 + rl] = xv.z;
                lds_x[(kk + 3) * 64 + rl] = xv.w;
                lds_w[(kk + 0) * 64 + rl] = wv.x;
                lds_w[(kk + 1) * 64 + rl] = wv.y;
                lds_w[(kk + 2) * 64 + rl] = wv.z;
                lds_w[(kk + 3) * 64 + rl] = wv.w;
            }
        }
        __syncthreads();
#pragma unroll 4
        for (int kk = 0; kk < 64; ++kk) {
            float4 xv = *(const float4*)(lds_x + kk * 64 + tb4 * 4);
            float4 wv = *(const float4*)(lds_w + kk * 64 + tj4 * 4);
            acc[0][0] += xv.x * wv.x; acc[0][1] += xv.x * wv.y;
            acc[0][2] += xv.x * wv.z; acc[0][3] += xv.x * wv.w;
            acc[1][0] += xv.y * wv.x; acc[1][1] += xv.y * wv.y;
            acc[1][2] += xv.y * wv.z; acc[1][3] += xv.y * wv.w;
            acc[2][0] += xv.z * wv.x; acc[2][1] += xv.z * wv.y;
            acc[2][2] += xv.z * wv.z; acc[2][3] += xv.z * wv.w;
            acc[3][0] += xv.w * wv.x; acc[3][1] += xv.w * wv.y;
            acc[3][2] += xv.w * wv.z; acc[3][3] += xv.w * wv.w;
        }
    }
#pragma unroll
    for (int ib = 0; ib < 4; ++ib) {
        const int row = tb4 * 4 + ib;
        const int jc = j0 + tj4 * 4;
        float4 r;
        r.x = acc[ib][0]; r.y = acc[ib][1]; r.z = acc[ib][2]; r.w = acc[ib][3];
        if (addmode == 1) {
            float4 bv = *(const float4*)(addp + jc);
            r.x += bv.x; r.y += bv.y; r.z += bv.z; r.w += bv.w;
        } else if (addmode == 2) {
            float4 bv = *(const float4*)(addp + (size_t)(orow0 + row) * addJW + jc);
            r.x += bv.x; r.y += bv.y; r.z += bv.z; r.w += bv.w;
        }
        if (obf) {
            u64 pv = (u64)f2b(r.x) | ((u64)f2b(r.y) << 16)
                   | ((u64)f2b(r.z) << 32) | ((u64)f2b(r.w) << 48);
            *(u64*)(obf + (size_t)(orow0 + row) * 512 + jc) = pv;
        } else {
            *(float4*)(outp + (size_t)(orow0 + row) * JW + jc) = r;
        }
    }
}

// ========== bf16 staging (plain cached loads, XOR-swizzled LDS) ==========
__device__ __forceinline__ void stage_plain(const u16* __restrict__ Xg, u16* sX) {
    const int tid = threadIdx.x;
#pragma unroll
    for (int p = 0; p < 16; ++p) {
        const int chunk = p * 256 + tid;
        const int row = chunk >> 6, cb16 = chunk & 63;
        const int src = row * 1024 + cb16 * 16;
        const int dst = src ^ ((row & 7) << 4);
        *(float4*)((char*)sX + dst) = *(const float4*)((const char*)Xg + src);
    }
}

// ========== single 64-col MFMA tile, K=512 ==========
__device__ __forceinline__ void mfma_tile(const u16* sX, const u16* __restrict__ Wg,
                                          f32x4 acc[4]) {
    const int tid = threadIdx.x;
    const int w = tid >> 6, l15 = tid & 15, lhi = (tid & 63) >> 4;
    const int arow = w * 16 + l15;
    const char* aptr = (const char*)sX;
    const int abase = arow * 1024 + lhi * 16;
    const int aswz = (arow & 7) << 4;
#pragma unroll 4
    for (int ks = 0; ks < 16; ++ks) {
        bf16x8 a = *(const bf16x8*)(aptr + ((abase + ks * 64) ^ aswz));
        const u16* wp = Wg + l15 * 512 + ks * 32 + lhi * 8;
        acc[0] = __builtin_amdgcn_mfma_f32_16x16x32_bf16(a, *(const bf16x8*)(wp), acc[0], 0, 0, 0);
        acc[1] = __builtin_amdgcn_mfma_f32_16x16x32_bf16(a, *(const bf16x8*)(wp + 16*512), acc[1], 0, 0, 0);
        acc[2] = __builtin_amdgcn_mfma_f32_16x16x32_bf16(a, *(const bf16x8*)(wp + 32*512), acc[2], 0, 0, 0);
        acc[3] = __builtin_amdgcn_mfma_f32_16x16x32_bf16(a, *(const bf16x8*)(wp + 48*512), acc[3], 0, 0, 0);
    }
}

// ========== merged 3-gate tile: 12 indep loads + 12 MFMAs per k-slice ==========
__device__ __forceinline__ void mfma_tile3(const u16* sX,
        const u16* __restrict__ W0, const u16* __restrict__ W1,
        const u16* __restrict__ W2, f32x4 a0[4], f32x4 a1[4], f32x4 a2[4]) {
    const int tid = threadIdx.x;
    const int w = tid >> 6, l15 = tid & 15, lhi = (tid & 63) >> 4;
    const int arow = w * 16 + l15;
    const char* aptr = (const char*)sX;
    const int abase = arow * 1024 + lhi * 16;
    const int aswz = (arow & 7) << 4;
#pragma unroll 2
    for (int ks = 0; ks < 16; ++ks) {
        bf16x8 a = *(const bf16x8*)(aptr + ((abase + ks * 64) ^ aswz));
        const int wo = l15 * 512 + ks * 32 + lhi * 8;
        const u16 *p0 = W0 + wo, *p1 = W1 + wo, *p2 = W2 + wo;
        bf16x8 b00 = *(const bf16x8*)(p0),         b01 = *(const bf16x8*)(p0 + 8192);
        bf16x8 b02 = *(const bf16x8*)(p0 + 16384), b03 = *(const bf16x8*)(p0 + 24576);
        bf16x8 b10 = *(const bf16x8*)(p1),         b11 = *(const bf16x8*)(p1 + 8192);
        bf16x8 b12 = *(const bf16x8*)(p1 + 16384), b13 = *(const bf16x8*)(p1 + 24576);
        bf16x8 b20 = *(const bf16x8*)(p2),         b21 = *(const bf16x8*)(p2 + 8192);
        bf16x8 b22 = *(const bf16x8*)(p2 + 16384), b23 = *(const bf16x8*)(p2 + 24576);
        a0[0] = __builtin_amdgcn_mfma_f32_16x16x32_bf16(a, b00, a0[0], 0, 0, 0);
        a0[1] = __builtin_amdgcn_mfma_f32_16x16x32_bf16(a, b01, a0[1], 0, 0, 0);
        a0[2] = __builtin_amdgcn_mfma_f32_16x16x32_bf16(a, b02, a0[2], 0, 0, 0);
        a0[3] = __builtin_amdgcn_mfma_f32_16x16x32_bf16(a, b03, a0[3], 0, 0, 0);
        a1[0] = __builtin_amdgcn_mfma_f32_16x16x32_bf16(a, b10, a1[0], 0, 0, 0);
        a1[1] = __builtin_amdgcn_mfma_f32_16x16x32_bf16(a, b11, a1[1], 0, 0, 0);
        a1[2] = __builtin_amdgcn_mfma_f32_16x16x32_bf16(a, b12, a1[2], 0, 0, 0);
        a1[3] = __builtin_amdgcn_mfma_f32_16x16x32_bf16(a, b13, a1[3], 0, 0, 0);
        a2[0] = __builtin_amdgcn_mfma_f32_16x16x32_bf16(a, b20, a2[0], 0, 0, 0);
        a2[1] = __builtin_amdgcn_mfma_f32_16x16x32_bf16(a, b21, a2[1], 0, 0, 0);
        a2[2] = __builtin_amdgcn_mfma_f32_16x16x32_bf16(a, b22, a2[2], 0, 0, 0);
        a2[3] = __builtin_amdgcn_mfma_f32_16x16x32_bf16(a, b23, a2[3], 0, 0, 0);
    }
}
__device__ __forceinline__ void zero4(f32x4 a[4]) {
    f32x4 z = {0.f, 0.f, 0.f, 0.f};
    a[0] = z; a[1] = z; a[2] = z; a[3] = z;
}

// =================== upfront: all static data + initial state ===============
__global__ __launch_bounds__(256)
void k_upfront(const int* __restrict__ inp, const float* __restrict__ hid,
               const float* __restrict__ ctxin, const float* __restrict__ init_att,
               const float* __restrict__ embW,
               const float* __restrict__ W_ih0, const float* __restrict__ b_ih0,
               const float* __restrict__ W_hh0, const float* __restrict__ W_hh1,
               const float* __restrict__ W_ih1, const float* __restrict__ W_q,
               const float* __restrict__ W_read, const float* __restrict__ b_read,
               const float* __restrict__ W_pre, const float* __restrict__ b_pre,
               float* __restrict__ wsf)
{
    __shared__ float lds_x[4096], lds_w[4096];
    u16* wsu = (u16*)wsf;
    const int jid = blockIdx.x, tid = threadIdx.x, rl = tid >> 2;
    if (jid < 768) {
        const int mt = jid / 24, jt = jid % 24, j0 = jt << 6;
        const int idx = inp[mt * 64 + rl];
        gemm64(embW + (size_t)idx * 512, W_ih0 + (size_t)(j0 + rl) * 1024,
               0, 8, lds_x, lds_w, wsf + OFF_EGI, 1536, mt << 6, j0, b_ih0, 1, 0, nullptr);
    } else if (jid < 1024) {
        const int r = jid - 768, mt = r >> 3, jt = r & 7, j0 = jt << 6;
        const int idx = inp[mt * 64 + rl];
        gemm64(embW + (size_t)idx * 512, W_read + (size_t)(j0 + rl) * 1536,
               0, 8, lds_x, lds_w, wsf + OFF_EREAD, 512, mt << 6, j0, b_read, 1, 0, nullptr);
    } else if (jid < 2048) {
        const int r = jid - 1024, mt = r >> 3, jt = r & 7, j0 = jt << 6;
        const int m = (mt << 6) + rl, b = m >> 7, s = m & 127;
        gemm64(ctxin + (size_t)((s << 6) + b) * 512, W_pre + (size_t)(j0 + rl) * 512,
               0, 8, lds_x, lds_w, nullptr, 512, mt << 6, j0, b_pre, 1, 0,
               wsu + UB_PREB);
    } else if (jid < 2272) {
        const int w = jid - 2048;
        if (w < 48) {
            for (int i = 0; i < 64; ++i) {
                int e = w * 16384 + i * 256 + tid;
                int j = e >> 9, k = e & 511;
                wsu[UB_WIH0C + e] = f2b(W_ih0[(size_t)j * 1024 + 512 + k]);
            }
        } else if (w < 96) {
            for (int i = 0; i < 64; ++i) {
                int e = (w - 48) * 16384 + i * 256 + tid;
                wsu[UB_WHH0 + e] = f2b(W_hh0[e]);
            }
        } else if (w < 144) {
            for (int i = 0; i < 64; ++i) {
                int e = (w - 96) * 16384 + i * 256 + tid;
                wsu[UB_WHH1 + e] = f2b(W_hh1[e]);
            }
        } else if (w < 192) {
            for (int i = 0; i < 64; ++i) {
                int e = (w - 144) * 16384 + i * 256 + tid;
                wsu[UB_WIH1 + e] = f2b(W_ih1[e]);
            }
        } else if (w < 208) {
            for (int i = 0; i < 64; ++i) {
                int e = (w - 192) * 16384 + i * 256 + tid;
                int j = e >> 9, k = e & 511;
                wsu[UB_WRO + e] = f2b(W_read[(size_t)j * 1536 + 512 + k]);
            }
        } else {
            for (int i = 0; i < 64; ++i) {
                int e = (w - 208) * 16384 + i * 256 + tid;
                int j = e >> 9, k = e & 511;
                wsu[UB_WRC + e] = f2b(W_read[(size_t)j * 1536 + 1024 + k]);
            }
        }
    } else if (jid < 2528) {
        // ctxT bf16 [b][s][e]
        const int w2 = jid - 2272;
        for (int rr = 0; rr < 32; ++rr) {
            const int r = w2 * 32 + rr;
            const int b = r >> 7, s = r & 127;
            const float* src = ctxin + ((size_t)s * 64 + b) * 512;
#pragma unroll
            for (int h = 0; h < 2; ++h) {
                int e = h * 256 + tid;
                wsu[UB_CTXT + (size_t)r * 512 + e] = f2b(src[e]);
            }
        }
    } else if (jid < 2544) {
        const int w3 = jid - 2528;
        for (int i = 0; i < 64; ++i) {
            int e = w3 * 16384 + i * 256 + tid;
            wsu[UB_WQ + e] = f2b(W_q[e]);
        }
    } else {
        // initial bf16 states into rotation slot 32
        const int job = jid - 2544;
        const float* src = job == 0 ? hid : (job == 1 ? hid + 32768 : init_att);
        u16* dst = wsu + (size_t)(job == 0 ? ROT_H0B : (job == 1 ? ROT_H1B : ROT_CTXB))
                 + (size_t)32 * 32768;
        for (int i = 0; i < 128; ++i) {
            int e = i * 256 + tid;
            dst[e] = f2b(src[e]);
        }
    }
}

// =================== persistent loop kernel (88 blocks) ===================
__global__ __launch_bounds__(256, 1)
void k_loop(const float* __restrict__ b_hh0, const float* __restrict__ b_ih1,
            const float* __restrict__ b_hh1, const float* __restrict__ hid,
            const float* __restrict__ maskp, const float* __restrict__ w_v,
            const float* __restrict__ W_copy, const float* __restrict__ b_copy,
            float* __restrict__ wsf, float* __restrict__ dout)
{
    __shared__ u16 sX[32768];   // 64KB staging / scratch
    u16* wsu = (u16*)wsf;
    const int blk = blockIdx.x, tid = threadIdx.x;
    const int w = tid >> 6, l15 = tid & 15, lhi = (tid & 63) >> 4;

    if (blk < 8) {
        // ===== A: layer-0 gates -> h0[t].  gh0 overlaps C(t-1). =====
        const int j = blk;
        float hp[4][4];
#pragma unroll
        for (int cb = 0; cb < 4; ++cb)
#pragma unroll
            for (int r = 0; r < 4; ++r)
                hp[cb][r] = hid[(w * 16 + lhi * 4 + r) * 512 + j * 64 + cb * 16 + l15];

        for (int t = 0; t < 32; ++t) {
            const size_t slot = t, slotp = (t == 0) ? 32 : (size_t)(t - 1);
            // EGI prefetch (static, off critical path)
            float eg0[4][4], eg1[4][4], eg2[4][4];
            {
                const float* EG = wsf + OFF_EGI + (size_t)t * 98304;
#pragma unroll
                for (int cb = 0; cb < 4; ++cb) {
                    const int gc = j * 64 + cb * 16 + l15;
#pragma unroll
                    for (int r = 0; r < 4; ++r) {
                        const float* eg = EG + (size_t)(w * 16 + lhi * 4 + r) * 1536;
                        eg0[cb][r] = eg[gc];
                        eg1[cb][r] = eg[512 + gc];
                        eg2[cb][r] = eg[1024 + gc];
                    }
                }
            }
            f32x4 aR[4], aZ[4], aIN[4], aHN[4];
            zero4(aR); zero4(aZ); zero4(aIN); zero4(aHN);
            // ---- gh0: needs only h0[t-1] (PH_A(t-1)) — overlaps C(t-1) ----
            if (t > 0) bar_wait1(cptr(wsf, t - 1, PH_A, 0), 8);
            stage_plain(wsu + ROT_H0B + slotp * 32768, sX);
            __syncthreads();
            mfma_tile3(sX, wsu + UB_WHH0 + (size_t)(j * 64) * 512,
                           wsu + UB_WHH0 + (size_t)(512 + j * 64) * 512,
                           wsu + UB_WHH0 + (size_t)(1024 + j * 64) * 512, aR, aZ, aHN);
            __syncthreads();
            // ---- gi0: needs ctx[t-1] (PH_CT(t-1)) — the critical wait ----
            if (t > 0) bar_wait8(cptr(wsf, t - 1, PH_CT, 0), 8);
            stage_plain(wsu + ROT_CTXB + slotp * 32768, sX);
            __syncthreads();
            mfma_tile3(sX, wsu + UB_WIH0C + (size_t)(j * 64) * 512,
                           wsu + UB_WIH0C + (size_t)(512 + j * 64) * 512,
                           wsu + UB_WIH0C + (size_t)(1024 + j * 64) * 512, aR, aZ, aIN);
            __syncthreads();
            // ---- combine + publish ----
            u16* tile = sX;
#pragma unroll
            for (int cb = 0; cb < 4; ++cb) {
                const int lc = cb * 16 + l15, gc = j * 64 + lc;
                const float brr = b_hh0[gc], bzz = b_hh0[512 + gc], bnn = b_hh0[1024 + gc];
#pragma unroll
                for (int r = 0; r < 4; ++r) {
                    const int row = w * 16 + lhi * 4 + r;
                    float rr = sigm(aR[cb][r] + eg0[cb][r] + brr);
                    float zz = sigm(aZ[cb][r] + eg1[cb][r] + bzz);
                    float nn = tanh_(aIN[cb][r] + eg2[cb][r] + rr * (aHN[cb][r] + bnn));
                    float v = (1.f - zz) * nn + zz * hp[cb][r];
                    hp[cb][r] = v;
                    tile[row * 64 + lc] = f2b(v);
                    if (t == 31) dout[OO_HID + row * 512 + gc] = v;
                }
            }
            __syncthreads();
            {
                u16* dst = wsu + ROT_H0B + slot * 32768 + j * 64;
#pragma unroll
                for (int i = 0; i < 4; ++i) {
                    int e = i * 256 + tid, row = e >> 4, c = e & 15;
                    sta8(dst + (size_t)row * 512 + c * 4, *(const u64*)(tile + row * 64 + c * 4));
                }
            }
            bar_arrive(cptr(wsf, t, PH_A, 0));
        }
    } else if (blk < 16) {
        // ===== B: layer-1 gates -> h1/out[t].  gh1 overlaps A(t)/C(t-1). =====
        const int j = blk - 8;
        float hp[4][4];
#pragma unroll
        for (int cb = 0; cb < 4; ++cb)
#pragma unroll
            for (int r = 0; r < 4; ++r)
                hp[cb][r] = hid[32768 + (w * 16 + lhi * 4 + r) * 512 + j * 64 + cb * 16 + l15];

        for (int t = 0; t < 32; ++t) {
            const size_t slot = t, slotp = (t == 0) ? 32 : (size_t)(t - 1);
            f32x4 aR[4], aZ[4], aIN[4], aHN[4];
            zero4(aR); zero4(aZ); zero4(aIN); zero4(aHN);
            // ---- gh1: needs only h1[t-1] — overlaps A(t) ----
            if (t > 0) bar_wait1(cptr(wsf, t - 1, PH_B, 0), 8);
            stage_plain(wsu + ROT_H1B + slotp * 32768, sX);
            __syncthreads();
            mfma_tile3(sX, wsu + UB_WHH1 + (size_t)(j * 64) * 512,
                           wsu + UB_WHH1 + (size_t)(512 + j * 64) * 512,
                           wsu + UB_WHH1 + (size_t)(1024 + j * 64) * 512, aR, aZ, aHN);
            __syncthreads();
            // ---- gi1: needs h0[t] (PH_A(t)) — the critical wait ----
            bar_wait1(cptr(wsf, t, PH_A, 0), 8);
            stage_plain(wsu + ROT_H0B + slot * 32768, sX);
            __syncthreads();
            mfma_tile3(sX, wsu + UB_WIH1 + (size_t)(j * 64) * 512,
                           wsu + UB_WIH1 + (size_t)(512 + j * 64) * 512,
                           wsu + UB_WIH1 + (size_t)(1024 + j * 64) * 512, aR, aZ, aIN);
            __syncthreads();
            // ---- combine + publish ----
            u16* tile = sX;
#pragma unroll
            for (int cb = 0; cb < 4; ++cb) {
                const int lc = cb * 16 + l15, gc = j * 64 + lc;
                const float bir = b_ih1[gc] + b_hh1[gc];
                const float biz = b_ih1[512 + gc] + b_hh1[512 + gc];
                const float bin_ = b_ih1[1024 + gc];
                const float bhn = b_hh1[1024 + gc];
#pragma unroll
                for (int r = 0; r < 4; ++r) {
                    const int row = w * 16 + lhi * 4 + r;
                    float rr = sigm(aR[cb][r] + bir);
                    float zz = sigm(aZ[cb][r] + biz);
                    float nn = tanh_(aIN[cb][r] + bin_ + rr * (aHN[cb][r] + bhn));
                    float v = (1.f - zz) * nn + zz * hp[cb][r];
                    hp[cb][r] = v;
                    tile[row * 64 + lc] = f2b(v);
                    if (t == 31) dout[OO_HID + 32768 + row * 512 + gc] = v;
                }
            }
            __syncthreads();
            {
                u16* dst = wsu + ROT_H1B + slot * 32768 + j * 64;
#pragma unroll
                for (int i = 0; i < 4; ++i) {
                    int e = i * 256 + tid, row = e >> 4, c = e & 15;
                    sta8(dst + (size_t)row * 512 + c * 4, *(const u64*)(tile + row * 64 + c * 4));
                }
            }
            bar_arrive(cptr(wsf, t, PH_B, 0));
        }
    } else if (blk < 80) {
        // ================= C: per-b attention =================
        const int b = blk - 16;
        float* sf = (float*)sX;
        float* s_out  = sf;            // 512
        float* s_q    = sf + 512;      // 512
        float* s_e    = sf + 1024;     // 128
        float* s_at   = sf + 1152;     // 128
        float* s_ctx  = sf + 1280;     // 512
        float* s_red  = sf + 1792;     // 256
        float* s_part = sf + 2048;     // 256
        float* s_ctxp = sf + 2304;     // 4*512
        float* s_wv   = sf + 4352;     // 512 (persistent)
        float* s_msk  = sf + 4864;     // 128 (persistent)
        float* s_wcp  = sf + 4992;     // 1024 (persistent)

        for (int i = tid; i < 512; i += 256) s_wv[i] = w_v[i];
        for (int i = tid; i < 1024; i += 256) s_wcp[i] = W_copy[i];
        if (tid < 128) s_msk[tid] = (maskp[b * 128 + tid] > 0.5f) ? -3.0e38f : 0.0f;
        __syncthreads();

        for (int t = 0; t < 32; ++t) {
            const size_t slot = t;
            bar_wait1(cptr(wsf, t, PH_B, 0), 8);
            {   // out[b] = h1[t][b]
                const u16* ob = wsu + ROT_H1B + slot * 32768 + b * 512;
                const int c0 = tid * 2;
                unsigned pv = *(const unsigned*)(ob + c0);
                s_out[c0] = b2f(pv & 0xffffu);
                s_out[c0 + 1] = b2f(pv >> 16);
            }
            __syncthreads();
            {   // q = out @ W_q^T
                const u16* wq0 = wsu + UB_WQ + (size_t)tid * 512;
                const u16* wq1 = wq0 + (size_t)256 * 512;
                float q0 = 0.f, q1 = 0.f;
#pragma unroll 8
                for (int i = 0; i < 64; ++i) {
                    bf16x8 w0 = *(const bf16x8*)(wq0 + i * 8);
                    bf16x8 w1 = *(const bf16x8*)(wq1 + i * 8);
#pragma unroll
                    for (int k2 = 0; k2 < 8; ++k2) {
                        float ov = s_out[i * 8 + k2];
                        q0 += ov * bfe(w0, k2);
                        q1 += ov * bfe(w1, k2);
                    }
                }
                s_q[tid] = q0; s_q[tid + 256] = q1;
            }
            __syncthreads();
            {   // energy: thread = (s, half)
                const int s = tid >> 1, sh = tid & 1;
                const u16* prep = wsu + UB_PREB + (((size_t)b * 128 + s) << 9) + (sh << 8);
                float part = 0.f;
#pragma unroll 4
                for (int i = 0; i < 32; ++i) {
                    bf16x8 v = *(const bf16x8*)(prep + i * 8);
#pragma unroll
                    for (int k2 = 0; k2 < 8; ++k2) {
                        const int a = (sh << 8) + i * 8 + k2;
                        part += tanh_(bfe(v, k2) + s_q[a]) * s_wv[a];
                    }
                }
                s_part[tid] = part;
            }
            __syncthreads();
            if (tid < 128) s_e[tid] = s_part[tid * 2] + s_part[tid * 2 + 1] + s_msk[tid];
            __syncthreads();
            if (tid < 64) {   // softmax over S=128
                float e0 = s_e[tid], e1 = s_e[tid + 64];
                float mx = fmaxf(e0, e1);
#pragma unroll
                for (int d2 = 1; d2 < 64; d2 <<= 1) mx = fmaxf(mx, __shfl_xor(mx, d2, 64));
                float x0 = __expf(e0 - mx), x1 = __expf(e1 - mx);
                float sm = x0 + x1;
#pragma unroll
                for (int d2 = 1; d2 < 64; d2 <<= 1) sm += __shfl_xor(sm, d2, 64);
                float inv = 1.f / sm;
                x0 *= inv; x1 *= inv;
                s_at[tid] = x0; s_at[tid + 64] = x1;
                float* co = dout + OO_C + ((size_t)t * 64 + b) * 128;
                co[tid] = x0; co[tid + 64] = x1;
                if (t == 31) {
                    dout[OO_AL + b * 128 + tid] = x0;
                    dout[OO_AL + b * 128 + tid + 64] = x1;
                }
            }
            __syncthreads();
            {   // ctx gather: wave-parallel over s
                const u16* ct = wsu + UB_CTXT + (size_t)b * 65536;
                const int ln = tid & 63;
                float ac[8] = {0.f,0.f,0.f,0.f,0.f,0.f,0.f,0.f};
#pragma unroll 4
                for (int si = 0; si < 32; ++si) {
                    const int s2 = w * 32 + si;
                    const float at = s_at[s2];
                    bf16x8 v = *(const bf16x8*)(ct + (size_t)s2 * 512 + ln * 8);
#pragma unroll
                    for (int k2 = 0; k2 < 8; ++k2) ac[k2] = fmaf(at, bfe(v, k2), ac[k2]);
                }
#pragma unroll
                for (int k2 = 0; k2 < 8; ++k2) s_ctxp[w * 512 + ln * 8 + k2] = ac[k2];
            }
            __syncthreads();
            {   // combine 4 wave-partials; publish ctx
                const int e0 = tid * 2;
                float c0 = s_ctxp[e0] + s_ctxp[512 + e0] + s_ctxp[1024 + e0] + s_ctxp[1536 + e0];
                float c1 = s_ctxp[e0 + 1] + s_ctxp[512 + e0 + 1] + s_ctxp[1024 + e0 + 1] + s_ctxp[1536 + e0 + 1];
                s_ctx[e0] = c0; s_ctx[e0 + 1] = c1;
                sta4(wsu + ROT_CTXB + slot * 32768 + b * 512 + e0,
                     (unsigned)f2b(c0) | ((unsigned)f2b(c1) << 16));
                if (t == 31) {
                    dout[OO_CTXF + b * 512 + e0] = c0;
                    dout[OO_CTXF + b * 512 + e0 + 1] = c1;
                }
            }
            bar_arrive(cptr(wsf, t, PH_CT, b >> 3));   // grouped arrival
            {   // copy gate (off critical path)
                const int i2 = tid * 2;
                float part = s_out[i2] * s_wcp[i2] + s_ctx[i2] * s_wcp[512 + i2]
                           + s_out[i2 + 1] * s_wcp[i2 + 1] + s_ctx[i2 + 1] * s_wcp[512 + i2 + 1];
                s_red[tid] = part;
                __syncthreads();
                for (int d2 = 128; d2 > 0; d2 >>= 1) {
                    if (tid < d2) s_red[tid] += s_red[tid + d2];
                    __syncthreads();
                }
                if (tid == 0)
                    dout[OO_CP + t * 64 + b] = sigm(s_red[0] + b_copy[0]);
            }
        }
    } else {
        // ============ RO+maxout track (8 blocks, off critical path) ============
        const int j = blk - 80;
        for (int tp = 0; tp < 32; ++tp) {
            bar_wait1(cptr(wsf, tp, PH_B, 0), 8);
            stage_plain(wsu + ROT_H1B + (size_t)tp * 32768, sX);
            __syncthreads();
            f32x4 acc[4];
            zero4(acc);
            mfma_tile(sX, wsu + UB_WRO + (size_t)(j * 64) * 512, acc);
            bar_wait8(cptr(wsf, tp, PH_CT, 0), 8);
            __syncthreads();
            stage_plain(wsu + ROT_CTXB + (size_t)tp * 32768, sX);
            __syncthreads();
            mfma_tile(sX, wsu + UB_WRC + (size_t)(j * 64) * 512, acc);
            __syncthreads();
            float* ft = (float*)sX;
            const float* ER = wsf + OFF_EREAD + (size_t)tp * 32768;
#pragma unroll
            for (int cb = 0; cb < 4; ++cb) {
                const int lc = cb * 16 + l15;
#pragma unroll
                for (int r = 0; r < 4; ++r) {
                    const int row = w * 16 + lhi * 4 + r;
                    ft[row * 64 + lc] = acc[cb][r] + ER[(size_t)row * 512 + j * 64 + lc];
                }
            }
            __syncthreads();
#pragma unroll
            for (int i = 0; i < 8; ++i) {
                int e = i * 256 + tid, row = e >> 5, c2 = e & 31;
                dout[OO_G + (size_t)tp * 16384 + row * 256 + j * 32 + c2] =
                    fmaxf(ft[row * 64 + 2 * c2], ft[row * 64 + 2 * c2 + 1]);
            }
        }
    }
}

extern "C" void kernel_launch(void* const* d_in, const int* in_sizes, int n_in,
                              void* d_out, int out_size, void* d_ws, size_t ws_size,
                              hipStream_t stream) {
    const int*   inp      = (const int*)d_in[0];
    const float* hid      = (const float*)d_in[1];
    const float* ctxin    = (const float*)d_in[2];
    const float* maskp    = (const float*)d_in[3];
    const float* init_att = (const float*)d_in[4];
    const float* embW     = (const float*)d_in[5];
    const float* W_ih0    = (const float*)d_in[6];
    const float* b_ih0    = (const float*)d_in[7];
    const float* W_hh0    = (const float*)d_in[8];
    const float* b_hh0    = (const float*)d_in[9];
    const float* W_ih1    = (const float*)d_in[10];
    const float* b_ih1    = (const float*)d_in[11];
    const float* W_hh1    = (const float*)d_in[12];
    const float* b_hh1    = (const float*)d_in[13];
    const float* W_pre    = (const float*)d_in[14];
    const float* b_pre    = (const float*)d_in[15];
    const float* W_q      = (const float*)d_in[16];
    const float* w_v      = (const float*)d_in[17];
    const float* W_copy   = (const float*)d_in[18];
    const float* b_copy   = (const float*)d_in[19];
    const float* W_read   = (const float*)d_in[20];
    const float* b_read   = (const float*)d_in[21];
    float* dout = (float*)d_out;
    float* wsf  = (float*)d_ws;

    // zero the phase counters each call (byte offset OFF_CNT*4)
    hipMemsetAsync((char*)d_ws + (size_t)OFF_CNT * 4, 0, CNT_BYTES, stream);

    k_upfront<<<dim3(2547), dim3(256), 0, stream>>>(
        inp, hid, ctxin, init_att, embW, W_ih0, b_ih0, W_hh0, W_hh1, W_ih1, W_q,
        W_read, b_read, W_pre, b_pre, wsf);

    k_loop<<<dim3(88), dim3(256), 0, stream>>>(
        b_hh0, b_ih1, b_hh1, hid, maskp, w_v, W_copy, b_copy, wsf, dout);
}